// Round 5
// baseline (262.472 us; speedup 1.0000x reference)
//
#include <hip/hip_runtime.h>
#include <hip/hip_bf16.h>

// Problem constants (B,S,M,D,H,DH = 2,1024,1024,1024,16,64)
#define B_ 2
#define S_ 1024
#define M_ 1024
#define D_ 1024
#define H_ 16
#define DH_ 64
#define K_ 2048
#define R_ 4095

// finite stand-in for -inf (avoids inf arithmetic under fast-math)
#define NEG_BIG (-1e30f)

typedef unsigned short u16;
typedef short short8 __attribute__((ext_vector_type(8)));
typedef float f32x4 __attribute__((ext_vector_type(4)));

__device__ __forceinline__ u16 f2bf(float f) {
  __hip_bfloat16 h = __float2bfloat16(f);
  return *reinterpret_cast<u16*>(&h);
}
__device__ __forceinline__ float bf2f(u16 u) {
  __hip_bfloat16 h;
  *reinterpret_cast<u16*>(&h) = u;
  return __bfloat162float(h);
}

// async global->LDS, 16B per lane; LDS dest = wave-uniform base + lane*16
__device__ __forceinline__ void gll16(const void* g, const void* l) {
  __builtin_amdgcn_global_load_lds(
      (const __attribute__((address_space(1))) unsigned int*)g,
      (__attribute__((address_space(3))) unsigned int*)l, 16, 0, 0);
}

__device__ __forceinline__ f32x4 mfma16(short8 a, short8 b, f32x4 c) {
  return __builtin_amdgcn_mfma_f32_16x16x32_bf16(a, b, c, 0, 0, 0);
}

// ---------------- fused prep: LN(concat) + 4x weight transpose + pos tiled cvt ----------
// posT layout: [b][g<136][oct<8][r<16][j<8] bf16, so an attn pos-fragment load
// (rows g*16+lr, cols oct*8..+8) is ONE contiguous 1KB wave transaction.
__global__ __launch_bounds__(256) void prep_kernel(
    const float* __restrict__ hidden, const float* __restrict__ memory,
    const float* __restrict__ gamma, const float* __restrict__ beta,
    u16* __restrict__ cln,
    const float* __restrict__ W0, const float* __restrict__ W1,
    const float* __restrict__ W2, const float* __restrict__ W3,
    u16* __restrict__ O0, u16* __restrict__ O1,
    u16* __restrict__ O2, u16* __restrict__ O3,
    const float* __restrict__ pos, u16* __restrict__ posT) {
  __shared__ u16 tile[64][66];
  __shared__ float red[8];
  const int bx = blockIdx.x;
  const int t = threadIdx.x;

  if (bx < 4096) {  // LayerNorm row
    const int b = bx >> 11;
    const int idx = bx & (K_ - 1);
    const float* src = (idx < M_)
        ? memory + (size_t)(b * M_ + idx) * D_
        : hidden + (size_t)(b * S_ + (idx - M_)) * D_;
    const int lane = t & 63, w = t >> 6;
    float4 rv = ((const float4*)src)[t];
    float s = rv.x + rv.y + rv.z + rv.w;
    float ss = rv.x * rv.x + rv.y * rv.y + rv.z * rv.z + rv.w * rv.w;
#pragma unroll
    for (int m = 1; m < 64; m <<= 1) {
      s += __shfl_xor(s, m, 64);
      ss += __shfl_xor(ss, m, 64);
    }
    if (lane == 0) { red[w] = s; red[4 + w] = ss; }
    __syncthreads();
    s = red[0] + red[1] + red[2] + red[3];
    ss = red[4] + red[5] + red[6] + red[7];
    const float mu = s * (1.0f / D_);
    const float var = ss * (1.0f / D_) - mu * mu;
    const float rstd = rsqrtf(var + 1e-5f);
    float4 gv = ((const float4*)gamma)[t];
    float4 bv = ((const float4*)beta)[t];
    ushort4 ov;
    ov.x = f2bf((rv.x - mu) * rstd * gv.x + bv.x);
    ov.y = f2bf((rv.y - mu) * rstd * gv.y + bv.y);
    ov.z = f2bf((rv.z - mu) * rstd * gv.z + bv.z);
    ov.w = f2bf((rv.w - mu) * rstd * gv.w + bv.w);
    ((ushort4*)(cln + (size_t)bx * D_))[t] = ov;
    return;
  }
  if (bx < 5120) {  // weight transpose slab
    const int z = (bx - 4096) >> 8;
    const int rem = (bx - 4096) & 255;
    const float* in; u16* out;
    switch (z) {
      case 0:  in = W0; out = O0; break;
      case 1:  in = W1; out = O1; break;
      case 2:  in = W2; out = O2; break;
      default: in = W3; out = O3; break;
    }
    const int tx = t & 63, ty = t >> 6;
    const int k0 = (rem & 15) * 64, n0 = (rem >> 4) * 64;
#pragma unroll
    for (int i = ty; i < 64; i += 4)
      tile[i][tx] = f2bf(in[(size_t)(k0 + i) * D_ + n0 + tx]);
    __syncthreads();
#pragma unroll
    for (int i = ty; i < 64; i += 4)
      out[(size_t)(n0 + i) * D_ + k0 + tx] = tile[tx][i];
    return;
  }
  // pos f32 -> bf16, tiled: u enumerates (b, g, r, oct); 136 groups of 16 rows per batch
  {
    const int u = (bx - 5120) * 256 + t;    // [0, 34816)
    const int oct = u & 7;
    const int r = (u >> 3) & 15;
    const int g = (u >> 7) % 136;
    const int b = u / 17408;                // 136*128
    const int row = g * 16 + r;             // <= 2175 < R_ (always in-bounds)
    const float* s = pos + ((size_t)b * R_ + row) * 64 + oct * 8;
    float4 v0 = ((const float4*)s)[0];
    float4 v1 = ((const float4*)s)[1];
    ushort4 oA, oB;
    oA.x = f2bf(v0.x); oA.y = f2bf(v0.y); oA.z = f2bf(v0.z); oA.w = f2bf(v0.w);
    oB.x = f2bf(v1.x); oB.y = f2bf(v1.y); oB.z = f2bf(v1.z); oB.w = f2bf(v1.w);
    u16* d = posT + (size_t)(b * 136 + g) * 1024 + oct * 128 + r * 8;
    ((ushort4*)d)[0] = oA;
    ((ushort4*)d)[1] = oB;
  }
}

// row r of the "hidden slice" view -> row of c_ln
__device__ __forceinline__ int maprow_hidden(int r) {
  return r + ((r >> 10) << 10) + M_;
}

// ---------------- QKV GEMM: BK=64, XOR-swizzled staging, 3 blocks/CU ----------------
__global__ __launch_bounds__(256, 3) void gemm_qkv_kernel(
    const u16* __restrict__ A, const u16* __restrict__ Bt,
    u16* __restrict__ qb, u16* __restrict__ kb, u16* __restrict__ vbT) {
  __shared__ __align__(16) u16 As[128 * 64];   // 16 KB
  __shared__ __align__(16) u16 Bs[128 * 64];   // 16 KB
  const int t = threadIdx.x;
  const int lane = t & 63, w = t >> 6;
  const int wm = w >> 1, wn = w & 1;
  const int qd = lane >> 4, lr = lane & 15;
  const int m0 = blockIdx.y * 128, n0 = blockIdx.x * 128;
  if (n0 < 1024 && !(m0 & 1024)) return;   // dead Q tiles (memory rows)

  const int swz = ((t & 7) ^ ((t >> 3) & 7)) * 8;  // source-chunk swizzle
  const int c0 = (qd ^ (lr & 7)) * 8;
  const int c1 = c0 ^ 32;
  const int row8 = (t >> 3) & 7;

  f32x4 acc[4][4];
#pragma unroll
  for (int mt = 0; mt < 4; mt++)
#pragma unroll
    for (int nt = 0; nt < 4; nt++) acc[mt][nt] = (f32x4){0.f, 0.f, 0.f, 0.f};

  for (int kt = 0; kt < 1024; kt += 64) {
#pragma unroll
    for (int p = 0; p < 4; p++) {
      const int ra = w * 32 + p * 8 + row8;
      gll16(A + (size_t)(m0 + ra) * 1024 + kt + swz, As + (w * 32 + p * 8) * 64);
      gll16(Bt + (size_t)(n0 + ra) * 1024 + kt + swz, Bs + (w * 32 + p * 8) * 64);
    }
    __syncthreads();
    short8 a0[4], a1[4], b0[4], b1[4];
#pragma unroll
    for (int mt = 0; mt < 4; mt++) {
      a0[mt] = *(const short8*)&As[(wm * 64 + mt * 16 + lr) * 64 + c0];
      a1[mt] = *(const short8*)&As[(wm * 64 + mt * 16 + lr) * 64 + c1];
    }
#pragma unroll
    for (int nt = 0; nt < 4; nt++) {
      b0[nt] = *(const short8*)&Bs[(wn * 64 + nt * 16 + lr) * 64 + c0];
      b1[nt] = *(const short8*)&Bs[(wn * 64 + nt * 16 + lr) * 64 + c1];
    }
#pragma unroll
    for (int mt = 0; mt < 4; mt++)
#pragma unroll
      for (int nt = 0; nt < 4; nt++) {
        acc[mt][nt] = mfma16(a0[mt], b0[nt], acc[mt][nt]);
        acc[mt][nt] = mfma16(a1[mt], b1[nt], acc[mt][nt]);
      }
    __syncthreads();
  }

#pragma unroll
  for (int mt = 0; mt < 4; mt++)
#pragma unroll
    for (int nt = 0; nt < 4; nt++) {
      const int colb = n0 + wn * 64 + nt * 16;
      const int rowb = m0 + wm * 64 + mt * 16 + qd * 4;
      if (colb < 1024) {                               // Q (pre-scaled 1/32)
        const int qrow = ((rowb >> 11) << 10) | (rowb & 1023);
#pragma unroll
        for (int r = 0; r < 4; r++)
          qb[(size_t)(qrow + r) * 1024 + colb + lr] = f2bf(acc[mt][nt][r] * 0.03125f);
      } else if (colb < 2048) {                        // K row-major
        const int key = rowb & (K_ - 1);
        const int bq = rowb >> 11;
#pragma unroll
        for (int r = 0; r < 4; r++)
          kb[(size_t)(bq * K_ + key + r) * 1024 + (colb - 1024) + lr] = f2bf(acc[mt][nt][r]);
      } else {                                         // V transposed [b*H+h][dh][key]
        const int nn = colb - 2048 + lr;
        const int bh = ((rowb >> 11) << 4) | (nn >> 6);
        const int dh = nn & 63;
        const int key = rowb & (K_ - 1);
        ushort4 pk;
        pk.x = f2bf(acc[mt][nt][0]);
        pk.y = f2bf(acc[mt][nt][1]);
        pk.z = f2bf(acc[mt][nt][2]);
        pk.w = f2bf(acc[mt][nt][3]);
        *(ushort4*)&vbT[((size_t)bh * 64 + dh) * K_ + key] = pk;
      }
    }
}

// ---------------- out GEMM: 128x64 tiles (256 blocks), f32 out + LN residual ----------------
__global__ __launch_bounds__(256, 2) void out_gemm_kernel(
    const u16* __restrict__ A, const u16* __restrict__ Bt,
    const u16* __restrict__ resid, float* __restrict__ Cf) {
  __shared__ __align__(16) u16 As[128 * 32];
  __shared__ __align__(16) u16 Bs[64 * 32];
  const int t = threadIdx.x;
  const int lane = t & 63, w = t >> 6;
  const int wm = w >> 1, wn = w & 1;
  const int qd = lane >> 4, lr = lane & 15;
  const int m0 = blockIdx.y * 128, n0 = blockIdx.x * 64;

  const u16* Ag0 = A + (size_t)(m0 + (t >> 2)) * 1024 + (t & 3) * 8;
  const u16* Ag1 = Ag0 + (size_t)64 * 1024;
  const u16* Bg0 = Bt + (size_t)(n0 + (t >> 2)) * 1024 + (t & 3) * 8;

  f32x4 acc[4][2];
#pragma unroll
  for (int mt = 0; mt < 4; mt++)
#pragma unroll
    for (int nt = 0; nt < 2; nt++) acc[mt][nt] = (f32x4){0.f, 0.f, 0.f, 0.f};

  for (int kt = 0; kt < 1024; kt += 32) {
    gll16(Ag0 + kt, As + w * 512);
    gll16(Ag1 + kt, As + 2048 + w * 512);
    gll16(Bg0 + kt, Bs + w * 512);
    __syncthreads();
    short8 af[4], bfr[2];
#pragma unroll
    for (int mt = 0; mt < 4; mt++)
      af[mt] = *(const short8*)&As[(wm * 64 + mt * 16 + lr) * 32 + qd * 8];
#pragma unroll
    for (int nt = 0; nt < 2; nt++)
      bfr[nt] = *(const short8*)&Bs[(wn * 32 + nt * 16 + lr) * 32 + qd * 8];
#pragma unroll
    for (int mt = 0; mt < 4; mt++)
#pragma unroll
      for (int nt = 0; nt < 2; nt++)
        acc[mt][nt] = mfma16(af[mt], bfr[nt], acc[mt][nt]);
    __syncthreads();
  }

#pragma unroll
  for (int mt = 0; mt < 4; mt++)
#pragma unroll
    for (int nt = 0; nt < 2; nt++)
#pragma unroll
      for (int r = 0; r < 4; r++) {
        const int row = m0 + wm * 64 + mt * 16 + qd * 4 + r;
        const int col = n0 + wn * 32 + nt * 16 + lr;
        float v = acc[mt][nt][r] + bf2f(resid[(size_t)maprow_hidden(row) * 1024 + col]);
        Cf[(size_t)row * 1024 + col] = v;
      }
}

// ---------------- attention: split-K=2 + XCD-grouped mapping, no atomics --------------
// 1024 blocks; LDS 40960 B x 4 = 160 KiB -> 4 blocks/CU = 4 waves/SIMD (2x chain
// overlap vs monolithic). Each XCD owns 4 (b,h) groups -> K/V slab L2-resident
// (R4-proven). Per-CU pairing (qt,15-qt)x(half,1-half) = exactly 49 tiles/CU.
// Max-free softmax => exact partial combine. grid (1024).
__global__ __launch_bounds__(256, 4) void attn_kernel(
    const u16* __restrict__ qb, const u16* __restrict__ kb,
    const u16* __restrict__ vbT, const u16* __restrict__ posT,
    float* __restrict__ oh, float* __restrict__ lsumb) {
  __shared__ __align__(16) u16 Ks[2][64 * 64];   // 16 KB (Ks[1] aliases Q pre-loop)
  __shared__ __align__(16) u16 Vt[2][64 * 64];   // 16 KB  [dh][key]
  __shared__ __align__(16) u16 Pt[4][16 * 64];   // 8 KB wave-private P tiles (XOR-swizzled)

  const int t = threadIdx.x;
  const int lane = t & 63, w = t >> 6;
  const int qd = lane >> 4, lr = lane & 15;

  // XCD-grouped split-K mapping (bijective on 1024 blocks)
  const int flat = blockIdx.x;
  const int xcd = flat & 7;
  const int slot = flat >> 3;          // 0..127 within XCD
  const int s = slot >> 5;             // group-sub 0..3
  const int wi = slot & 31;            // within-group index
  const int g = s * 8 + xcd;           // (b,h) group 0..31
  const int h = g & 15;
  const int b = g >> 4;
  const int qt = (s & 1) ? 15 - (wi & 15) : (wi & 15);
  const int half = ((s >> 1) ^ (wi >> 4)) & 1;
  const int i0 = qt * 64;

  const int swz = ((t & 7) ^ ((t >> 3) & 7)) * 8;  // staging source-chunk swizzle
  const int c0 = (qd ^ (lr & 7)) * 8;              // fragment-read chunk offsets
  const int c1 = c0 ^ 32;
  const int row8 = t >> 3;

  // key-range split
  const int jmax = min(K_, i0 + 64 + M_);
  const int nt_total = jmax >> 6;
  const int nt0 = nt_total >> 1;
  const int t_start = half ? nt0 : 0;
  const int t_end = half ? nt_total : nt0;
  const int j0s = t_start * 64;
  const int jend = t_end * 64;

  // tiled pos fragment base: group for tile tt, frag pc is g0 + 4*tt + pc.
  // g0 = 63 - i0/16 - w >= 0; max group (incl. one-past-end prefetch) <= 135 < 136.
  const int g0 = 63 - (i0 >> 4) - w;
  const u16* pb0 = posT + (size_t)b * 139264 + qd * 128 + lr * 8;

  // ---- pre-loop staging: Q -> Ks[1], first K/V tile -> buf0 ----
#pragma unroll
  for (int rd = 0; rd < 2; rd++)
    gll16(qb + (size_t)(b * S_ + i0 + rd * 32 + row8) * 1024 + h * 64 + swz,
          &Ks[1][0] + rd * 2048 + w * 512);
#pragma unroll
  for (int rd = 0; rd < 2; rd++) {
    gll16(kb + (size_t)(b * K_ + j0s + rd * 32 + row8) * 1024 + h * 64 + swz,
          &Ks[0][0] + rd * 2048 + w * 512);
    gll16(vbT + (size_t)((b * H_ + h) * 64 + rd * 32 + row8) * K_ + j0s + swz,
          &Vt[0][0] + rd * 2048 + w * 512);
  }
  // preload pos fragments for first tile (registers, coalesced)
  short8 pg0[5], pg1[5];
  {
    const u16* pp = pb0 + (size_t)(g0 + 4 * t_start) * 1024;
#pragma unroll
    for (int pc = 0; pc < 5; pc++) {
      pg0[pc] = *(const short8*)(pp + pc * 1024);
      pg1[pc] = *(const short8*)(pp + pc * 1024 + 512);
    }
  }
  __syncthreads();
  const short8 aQ0 = *(const short8*)&Ks[1][(w * 16 + lr) * 64 + c0];
  const short8 aQ1 = *(const short8*)&Ks[1][(w * 16 + lr) * 64 + c1];

  f32x4 accO[4];
#pragma unroll
  for (int d = 0; d < 4; d++) accO[d] = (f32x4){0.f, 0.f, 0.f, 0.f};
  float lsum[4];
#pragma unroll
  for (int r = 0; r < 4; r++) lsum[r] = 0.f;

  int cur = 0;

  for (int j0 = j0s, tt = t_start; j0 < jend; j0 += 64, tt++) {
    __syncthreads();
    if (j0 + 64 < jend) {
      const int nxt = cur ^ 1;
#pragma unroll
      for (int rd = 0; rd < 2; rd++) {
        gll16(kb + (size_t)(b * K_ + j0 + 64 + rd * 32 + row8) * 1024 + h * 64 + swz,
              &Ks[nxt][0] + rd * 2048 + w * 512);
        gll16(vbT + (size_t)((b * H_ + h) * 64 + rd * 32 + row8) * K_ + j0 + 64 + swz,
              &Vt[nxt][0] + rd * 2048 + w * 512);
      }
    }

    // ---- Q @ pos-band^T: register-only MFMAs (operands prefetched last tile) ----
    f32x4 zp[5];
#pragma unroll
    for (int pc = 0; pc < 5; pc++) {
      f32x4 z = {0.f, 0.f, 0.f, 0.f};
      z = mfma16(aQ0, pg0[pc], z);
      zp[pc] = mfma16(aQ1, pg1[pc], z);
    }

    // ---- QK^T: 16 rows x 64 keys ----
    f32x4 sqk[4];
#pragma unroll
    for (int kc = 0; kc < 4; kc++) {
      const short8 bK0 = *(const short8*)&Ks[cur][(kc * 16 + lr) * 64 + c0];
      const short8 bK1 = *(const short8*)&Ks[cur][(kc * 16 + lr) * 64 + c1];
      f32x4 z = {0.f, 0.f, 0.f, 0.f};
      z = mfma16(aQ0, bK0, z);
      sqk[kc] = mfma16(aQ1, bK1, z);
    }

    // ---- prefetch next tile's pos fragments (groups bounded <= 135) ----
    {
      const u16* pn = pb0 + (size_t)(g0 + 4 * (tt + 1)) * 1024;
#pragma unroll
      for (int pc = 0; pc < 5; pc++) {
        pg0[pc] = *(const short8*)(pn + pc * 1024);
        pg1[pc] = *(const short8*)(pn + pc * 1024 + 512);
      }
    }

    // ---- shuffle-based skew gather + max-free softmax ----
    const bool tail = (j0 + 63 > i0 + w * 16 + M_);  // wave-uniform
    float p[4][4];
#pragma unroll
    for (int r = 0; r < 4; r++) {
      const int iL = qd * 4 + r;
      const int d = 15 + lr - iL;                    // [0,30]
      const int srcl = qd * 16 + (d & 15);
      const bool hi = (d >> 4) & 1;
      float g0s = __shfl(zp[0][r], srcl, 64);
      float g1s = __shfl(zp[1][r], srcl, 64);
      float g2s = __shfl(zp[2][r], srcl, 64);
      float g3s = __shfl(zp[3][r], srcl, 64);
      float g4s = __shfl(zp[4][r], srcl, 64);
      float s0 = sqk[0][r] + (hi ? g1s : g0s);
      float s1 = sqk[1][r] + (hi ? g2s : g1s);
      float s2 = sqk[2][r] + (hi ? g3s : g2s);
      float s3 = sqk[3][r] + (hi ? g4s : g3s);
      if (tail) {
        const int key = j0 + lr, lim = i0 + w * 16 + iL + M_;
        if (key      > lim) s0 = NEG_BIG;
        if (key + 16 > lim) s1 = NEG_BIG;
        if (key + 32 > lim) s2 = NEG_BIG;
        if (key + 48 > lim) s3 = NEG_BIG;
      }
      p[0][r] = __expf(s0);
      p[1][r] = __expf(s1);
      p[2][r] = __expf(s2);
      p[3][r] = __expf(s3);
      lsum[r] += p[0][r] + p[1][r] + p[2][r] + p[3][r];
    }

    // ---- P -> wave-private LDS (XOR chunk swizzle, stride 64) -> A-fragments ----
#pragma unroll
    for (int r = 0; r < 4; r++) {
      const int row = qd * 4 + r;
      const int cbase = row * 64;
      const int rx = row & 7;
      const int lo = lr & 7, hi8 = lr >> 3;
#pragma unroll
      for (int kc = 0; kc < 4; kc++)
        Pt[w][cbase + ((((kc << 1) | hi8) ^ rx) << 3) + lo] = f2bf(p[kc][r]);
    }
    __asm__ volatile("s_waitcnt lgkmcnt(0)" ::: "memory");
    const short8 aP0 = *(const short8*)&Pt[w][lr * 64 + ((qd ^ (lr & 7)) << 3)];
    const short8 aP1 = *(const short8*)&Pt[w][lr * 64 + (((qd + 4) ^ (lr & 7)) << 3)];

    // ---- P @ V ----
#pragma unroll
    for (int d2 = 0; d2 < 4; d2++) {
      const short8 bV0 = *(const short8*)&Vt[cur][(d2 * 16 + lr) * 64 + c0];
      const short8 bV1 = *(const short8*)&Vt[cur][(d2 * 16 + lr) * 64 + c1];
      accO[d2] = mfma16(aP0, bV0, accO[d2]);
      accO[d2] = mfma16(aP1, bV1, accO[d2]);
    }

    cur ^= 1;
  }

  // ---- epilogue: 16-lane reduce of lsum, plain f32 partial stores (no atomics) ----
#pragma unroll
  for (int r = 0; r < 4; r++) {
#pragma unroll
    for (int msk = 1; msk < 16; msk <<= 1) lsum[r] += __shfl_xor(lsum[r], msk, 64);
  }
  if (lr == 0) {
#pragma unroll
    for (int r = 0; r < 4; r++) {
      const int iG = i0 + w * 16 + qd * 4 + r;
      lsumb[half * 32768 + (b * H_ + h) * 1024 + iG] = lsum[r];
    }
  }
  float* op = oh + (size_t)half * 2097152;
#pragma unroll
  for (int d2 = 0; d2 < 4; d2++)
#pragma unroll
    for (int r = 0; r < 4; r++) {
      const int iG = i0 + w * 16 + qd * 4 + r;
      op[(size_t)(b * S_ + iG) * 1024 + h * 64 + d2 * 16 + lr] = accO[d2][r];
    }
}

// ---------------- combine: sum the two half-partials, normalize -> bf16 attn out -------
__global__ __launch_bounds__(256) void combine_kernel(
    const float* __restrict__ oh, const float* __restrict__ lsumb,
    u16* __restrict__ ab) {
  const int idx = blockIdx.x * 256 + threadIdx.x;   // f32x4 index, 524288 total
  const float4 a0 = ((const float4*)oh)[idx];
  const float4 a1 = ((const float4*)(oh + 2097152))[idx];
  const int flat = idx << 2;
  const int col = flat & 1023;
  const int i = (flat >> 10) & (S_ - 1);
  const int b = flat >> 20;
  const int h = col >> 6;
  const int li = (b * H_ + h) * 1024 + i;
  const float inv = 1.0f / (lsumb[li] + lsumb[32768 + li]);
  ushort4 o;
  o.x = f2bf((a0.x + a1.x) * inv);
  o.y = f2bf((a0.y + a1.y) * inv);
  o.z = f2bf((a0.z + a1.z) * inv);
  o.w = f2bf((a0.w + a1.w) * inv);
  ((ushort4*)ab)[idx] = o;
}

// ---------------- launch ----------------
extern "C" void kernel_launch(void* const* d_in, const int* in_sizes, int n_in,
                              void* d_out, int out_size, void* d_ws, size_t ws_size,
                              hipStream_t stream) {
  const float* hidden = (const float*)d_in[0];
  const float* pos    = (const float*)d_in[1];
  const float* memory = (const float*)d_in[2];
  // d_in[3] = mask (bool) — causality applied analytically, unused
  const float* Wq = (const float*)d_in[4];
  const float* Wk = (const float*)d_in[5];
  const float* Wv = (const float*)d_in[6];
  const float* Wo = (const float*)d_in[7];
  const float* gamma = (const float*)d_in[8];
  const float* beta  = (const float*)d_in[9];

  char* ws = (char*)d_ws;
  // Aliased layout (max offset 48 MB):
  //  ab reuses qb (qb dead after attn; ab written by combine).
  //  oh (16 MB f32 partials) overlays WqT/WkT/WvT (dead after gemm_qkv).
  u16* cln  = (u16*)(ws);                    // [0, 8 MB)
  u16* qb   = (u16*)(ws + 8388608);          // [8, 12 MB)   qb, later ab
  u16* kb   = (u16*)(ws + 12582912);         // [12, 20 MB)
  u16* vbT  = (u16*)(ws + 20971520);         // [20, 28 MB)
  u16* WoT  = (u16*)(ws + 29360128);         // [28, 30 MB)  live till out_gemm
  u16* posT = (u16*)(ws + 31457280);         // [30, 30.53 MB)
  float* lsumb = (float*)(ws + 32014336);    // 256 KB
  u16* WqT  = (u16*)(ws + 33554432);         // [32, 34 MB)  dead after qkv
  u16* WkT  = (u16*)(ws + 35651584);         // [34, 36 MB)  dead after qkv
  u16* WvT  = (u16*)(ws + 37748736);         // [36, 38 MB)  dead after qkv
  float* oh = (float*)(ws + 33554432);       // [32, 48 MB)  f32 partials (overlaps Ws)
  u16* ab   = qb;

  prep_kernel<<<dim3(5256), 256, 0, stream>>>(
      hidden, memory, gamma, beta, cln,
      Wq, Wk, Wv, Wo, WqT, WkT, WvT, WoT, pos, posT);
  gemm_qkv_kernel<<<dim3(24, 32), 256, 0, stream>>>(cln, WqT, qb, kb, vbT);
  attn_kernel<<<dim3(1024), 256, 0, stream>>>(qb, kb, vbT, posT, oh, lsumb);
  combine_kernel<<<dim3(2048), 256, 0, stream>>>(oh, lsumb, ab);
  out_gemm_kernel<<<dim3(16, 16), 256, 0, stream>>>(ab, WoT, cln, (float*)d_out);
}

// Round 6
// 205.433 us; speedup vs baseline: 1.2777x; 1.2777x over previous
//
#include <hip/hip_runtime.h>
#include <hip/hip_bf16.h>

// Problem constants (B,S,M,D,H,DH = 2,1024,1024,1024,16,64)
#define B_ 2
#define S_ 1024
#define M_ 1024
#define D_ 1024
#define H_ 16
#define DH_ 64
#define K_ 2048
#define R_ 4095

// finite stand-in for -inf (avoids inf arithmetic under fast-math)
#define NEG_BIG (-1e30f)

typedef unsigned short u16;
typedef short short8 __attribute__((ext_vector_type(8)));
typedef float f32x4 __attribute__((ext_vector_type(4)));

__device__ __forceinline__ u16 f2bf(float f) {
  __hip_bfloat16 h = __float2bfloat16(f);
  return *reinterpret_cast<u16*>(&h);
}
__device__ __forceinline__ float bf2f(u16 u) {
  __hip_bfloat16 h;
  *reinterpret_cast<u16*>(&h) = u;
  return __bfloat162float(h);
}

// async global->LDS, 16B per lane; LDS dest = wave-uniform base + lane*16
__device__ __forceinline__ void gll16(const void* g, const void* l) {
  __builtin_amdgcn_global_load_lds(
      (const __attribute__((address_space(1))) unsigned int*)g,
      (__attribute__((address_space(3))) unsigned int*)l, 16, 0, 0);
}

__device__ __forceinline__ f32x4 mfma16(short8 a, short8 b, f32x4 c) {
  return __builtin_amdgcn_mfma_f32_16x16x32_bf16(a, b, c, 0, 0, 0);
}

// ---------------- fused prep: LN(concat) + 4x weight transpose + pos tiled cvt ----------
// posT layout: [b][g<136][oct<8][r<16][j<8] bf16, so an attn pos-fragment load
// (rows g*16+lr, cols oct*8..+8) is ONE contiguous 1KB wave transaction.
__global__ __launch_bounds__(256) void prep_kernel(
    const float* __restrict__ hidden, const float* __restrict__ memory,
    const float* __restrict__ gamma, const float* __restrict__ beta,
    u16* __restrict__ cln,
    const float* __restrict__ W0, const float* __restrict__ W1,
    const float* __restrict__ W2, const float* __restrict__ W3,
    u16* __restrict__ O0, u16* __restrict__ O1,
    u16* __restrict__ O2, u16* __restrict__ O3,
    const float* __restrict__ pos, u16* __restrict__ posT) {
  __shared__ u16 tile[64][66];
  __shared__ float red[8];
  const int bx = blockIdx.x;
  const int t = threadIdx.x;

  if (bx < 4096) {  // LayerNorm row
    const int b = bx >> 11;
    const int idx = bx & (K_ - 1);
    const float* src = (idx < M_)
        ? memory + (size_t)(b * M_ + idx) * D_
        : hidden + (size_t)(b * S_ + (idx - M_)) * D_;
    const int lane = t & 63, w = t >> 6;
    float4 rv = ((const float4*)src)[t];
    float s = rv.x + rv.y + rv.z + rv.w;
    float ss = rv.x * rv.x + rv.y * rv.y + rv.z * rv.z + rv.w * rv.w;
#pragma unroll
    for (int m = 1; m < 64; m <<= 1) {
      s += __shfl_xor(s, m, 64);
      ss += __shfl_xor(ss, m, 64);
    }
    if (lane == 0) { red[w] = s; red[4 + w] = ss; }
    __syncthreads();
    s = red[0] + red[1] + red[2] + red[3];
    ss = red[4] + red[5] + red[6] + red[7];
    const float mu = s * (1.0f / D_);
    const float var = ss * (1.0f / D_) - mu * mu;
    const float rstd = rsqrtf(var + 1e-5f);
    float4 gv = ((const float4*)gamma)[t];
    float4 bv = ((const float4*)beta)[t];
    ushort4 ov;
    ov.x = f2bf((rv.x - mu) * rstd * gv.x + bv.x);
    ov.y = f2bf((rv.y - mu) * rstd * gv.y + bv.y);
    ov.z = f2bf((rv.z - mu) * rstd * gv.z + bv.z);
    ov.w = f2bf((rv.w - mu) * rstd * gv.w + bv.w);
    ((ushort4*)(cln + (size_t)bx * D_))[t] = ov;
    return;
  }
  if (bx < 5120) {  // weight transpose slab
    const int z = (bx - 4096) >> 8;
    const int rem = (bx - 4096) & 255;
    const float* in; u16* out;
    switch (z) {
      case 0:  in = W0; out = O0; break;
      case 1:  in = W1; out = O1; break;
      case 2:  in = W2; out = O2; break;
      default: in = W3; out = O3; break;
    }
    const int tx = t & 63, ty = t >> 6;
    const int k0 = (rem & 15) * 64, n0 = (rem >> 4) * 64;
#pragma unroll
    for (int i = ty; i < 64; i += 4)
      tile[i][tx] = f2bf(in[(size_t)(k0 + i) * D_ + n0 + tx]);
    __syncthreads();
#pragma unroll
    for (int i = ty; i < 64; i += 4)
      out[(size_t)(n0 + i) * D_ + k0 + tx] = tile[tx][i];
    return;
  }
  // pos f32 -> bf16, tiled: u enumerates (b, g, r, oct); 136 groups of 16 rows per batch
  {
    const int u = (bx - 5120) * 256 + t;    // [0, 34816)
    const int oct = u & 7;
    const int r = (u >> 3) & 15;
    const int g = (u >> 7) % 136;
    const int b = u / 17408;                // 136*128
    const int row = g * 16 + r;             // <= 2175 < R_ (always in-bounds)
    const float* s = pos + ((size_t)b * R_ + row) * 64 + oct * 8;
    float4 v0 = ((const float4*)s)[0];
    float4 v1 = ((const float4*)s)[1];
    ushort4 oA, oB;
    oA.x = f2bf(v0.x); oA.y = f2bf(v0.y); oA.z = f2bf(v0.z); oA.w = f2bf(v0.w);
    oB.x = f2bf(v1.x); oB.y = f2bf(v1.y); oB.z = f2bf(v1.z); oB.w = f2bf(v1.w);
    u16* d = posT + (size_t)(b * 136 + g) * 1024 + oct * 128 + r * 8;
    ((ushort4*)d)[0] = oA;
    ((ushort4*)d)[1] = oB;
  }
}

// row r of the "hidden slice" view -> row of c_ln
__device__ __forceinline__ int maprow_hidden(int r) {
  return r + ((r >> 10) << 10) + M_;
}

// ---------------- QKV GEMM: BK=64, XOR-swizzled staging, 3 blocks/CU ----------------
__global__ __launch_bounds__(256, 3) void gemm_qkv_kernel(
    const u16* __restrict__ A, const u16* __restrict__ Bt,
    u16* __restrict__ qb, u16* __restrict__ kb, u16* __restrict__ vbT) {
  __shared__ __align__(16) u16 As[128 * 64];   // 16 KB
  __shared__ __align__(16) u16 Bs[128 * 64];   // 16 KB
  const int t = threadIdx.x;
  const int lane = t & 63, w = t >> 6;
  const int wm = w >> 1, wn = w & 1;
  const int qd = lane >> 4, lr = lane & 15;
  const int m0 = blockIdx.y * 128, n0 = blockIdx.x * 128;
  if (n0 < 1024 && !(m0 & 1024)) return;   // dead Q tiles (memory rows)

  const int swz = ((t & 7) ^ ((t >> 3) & 7)) * 8;  // source-chunk swizzle
  const int c0 = (qd ^ (lr & 7)) * 8;
  const int c1 = c0 ^ 32;
  const int row8 = (t >> 3) & 7;

  f32x4 acc[4][4];
#pragma unroll
  for (int mt = 0; mt < 4; mt++)
#pragma unroll
    for (int nt = 0; nt < 4; nt++) acc[mt][nt] = (f32x4){0.f, 0.f, 0.f, 0.f};

  for (int kt = 0; kt < 1024; kt += 64) {
#pragma unroll
    for (int p = 0; p < 4; p++) {
      const int ra = w * 32 + p * 8 + row8;
      gll16(A + (size_t)(m0 + ra) * 1024 + kt + swz, As + (w * 32 + p * 8) * 64);
      gll16(Bt + (size_t)(n0 + ra) * 1024 + kt + swz, Bs + (w * 32 + p * 8) * 64);
    }
    __syncthreads();
    short8 a0[4], a1[4], b0[4], b1[4];
#pragma unroll
    for (int mt = 0; mt < 4; mt++) {
      a0[mt] = *(const short8*)&As[(wm * 64 + mt * 16 + lr) * 64 + c0];
      a1[mt] = *(const short8*)&As[(wm * 64 + mt * 16 + lr) * 64 + c1];
    }
#pragma unroll
    for (int nt = 0; nt < 4; nt++) {
      b0[nt] = *(const short8*)&Bs[(wn * 64 + nt * 16 + lr) * 64 + c0];
      b1[nt] = *(const short8*)&Bs[(wn * 64 + nt * 16 + lr) * 64 + c1];
    }
#pragma unroll
    for (int mt = 0; mt < 4; mt++)
#pragma unroll
      for (int nt = 0; nt < 4; nt++) {
        acc[mt][nt] = mfma16(a0[mt], b0[nt], acc[mt][nt]);
        acc[mt][nt] = mfma16(a1[mt], b1[nt], acc[mt][nt]);
      }
    __syncthreads();
  }

#pragma unroll
  for (int mt = 0; mt < 4; mt++)
#pragma unroll
    for (int nt = 0; nt < 4; nt++) {
      const int colb = n0 + wn * 64 + nt * 16;
      const int rowb = m0 + wm * 64 + mt * 16 + qd * 4;
      if (colb < 1024) {                               // Q (pre-scaled 1/32)
        const int qrow = ((rowb >> 11) << 10) | (rowb & 1023);
#pragma unroll
        for (int r = 0; r < 4; r++)
          qb[(size_t)(qrow + r) * 1024 + colb + lr] = f2bf(acc[mt][nt][r] * 0.03125f);
      } else if (colb < 2048) {                        // K row-major
        const int key = rowb & (K_ - 1);
        const int bq = rowb >> 11;
#pragma unroll
        for (int r = 0; r < 4; r++)
          kb[(size_t)(bq * K_ + key + r) * 1024 + (colb - 1024) + lr] = f2bf(acc[mt][nt][r]);
      } else {                                         // V transposed [b*H+h][dh][key]
        const int nn = colb - 2048 + lr;
        const int bh = ((rowb >> 11) << 4) | (nn >> 6);
        const int dh = nn & 63;
        const int key = rowb & (K_ - 1);
        ushort4 pk;
        pk.x = f2bf(acc[mt][nt][0]);
        pk.y = f2bf(acc[mt][nt][1]);
        pk.z = f2bf(acc[mt][nt][2]);
        pk.w = f2bf(acc[mt][nt][3]);
        *(ushort4*)&vbT[((size_t)bh * 64 + dh) * K_ + key] = pk;
      }
    }
}

// ---------------- out GEMM: 128x64 tiles (256 blocks), f32 out + LN residual ----------------
__global__ __launch_bounds__(256, 2) void out_gemm_kernel(
    const u16* __restrict__ A, const u16* __restrict__ Bt,
    const u16* __restrict__ resid, float* __restrict__ Cf) {
  __shared__ __align__(16) u16 As[128 * 32];
  __shared__ __align__(16) u16 Bs[64 * 32];
  const int t = threadIdx.x;
  const int lane = t & 63, w = t >> 6;
  const int wm = w >> 1, wn = w & 1;
  const int qd = lane >> 4, lr = lane & 15;
  const int m0 = blockIdx.y * 128, n0 = blockIdx.x * 64;

  const u16* Ag0 = A + (size_t)(m0 + (t >> 2)) * 1024 + (t & 3) * 8;
  const u16* Ag1 = Ag0 + (size_t)64 * 1024;
  const u16* Bg0 = Bt + (size_t)(n0 + (t >> 2)) * 1024 + (t & 3) * 8;

  f32x4 acc[4][2];
#pragma unroll
  for (int mt = 0; mt < 4; mt++)
#pragma unroll
    for (int nt = 0; nt < 2; nt++) acc[mt][nt] = (f32x4){0.f, 0.f, 0.f, 0.f};

  for (int kt = 0; kt < 1024; kt += 32) {
    gll16(Ag0 + kt, As + w * 512);
    gll16(Ag1 + kt, As + 2048 + w * 512);
    gll16(Bg0 + kt, Bs + w * 512);
    __syncthreads();
    short8 af[4], bfr[2];
#pragma unroll
    for (int mt = 0; mt < 4; mt++)
      af[mt] = *(const short8*)&As[(wm * 64 + mt * 16 + lr) * 32 + qd * 8];
#pragma unroll
    for (int nt = 0; nt < 2; nt++)
      bfr[nt] = *(const short8*)&Bs[(wn * 32 + nt * 16 + lr) * 32 + qd * 8];
#pragma unroll
    for (int mt = 0; mt < 4; mt++)
#pragma unroll
      for (int nt = 0; nt < 2; nt++)
        acc[mt][nt] = mfma16(af[mt], bfr[nt], acc[mt][nt]);
    __syncthreads();
  }

#pragma unroll
  for (int mt = 0; mt < 4; mt++)
#pragma unroll
    for (int nt = 0; nt < 2; nt++)
#pragma unroll
      for (int r = 0; r < 4; r++) {
        const int row = m0 + wm * 64 + mt * 16 + qd * 4 + r;
        const int col = n0 + wn * 32 + nt * 16 + lr;
        float v = acc[mt][nt][r] + bf2f(resid[(size_t)maprow_hidden(row) * 1024 + col]);
        Cf[(size_t)row * 1024 + col] = v;
      }
}

// ---------------- attention: R4 structure + ONE-TILE PV PIPELINE -----------------------
// Monolithic per-(b,h,qt), XCD-grouped remap (FETCH 12 MB proven). V triple-buffered;
// PV(t-1) issues inside iter t between QK(t) and softmax(t): its ds_reads+MFMAs overlap
// the shuffle/exp VALU phase, removing PV from the serial chain. setprio(1) around the
// MFMA cluster. LDS 48 KB, 2 blocks/CU. grid (16, H, B).
__global__ __launch_bounds__(256, 2) void attn_kernel(
    const u16* __restrict__ qb, const u16* __restrict__ kb,
    const u16* __restrict__ vbT, const u16* __restrict__ posT,
    u16* __restrict__ ab) {
  __shared__ __align__(16) u16 Ks[2][64 * 64];   // 16 KB (Ks[1] aliases Q pre-loop)
  __shared__ __align__(16) u16 Vt[3][64 * 64];   // 24 KB  [dh][key], triple-buffered
  __shared__ __align__(16) u16 Pt[4][16 * 64];   // 8 KB wave-private P tiles (XOR-swizzled)

  const int t = threadIdx.x;
  const int lane = t & 63, w = t >> 6;
  const int qd = lane >> 4, lr = lane & 15;

  // XCD-grouping remap (bijective on 512 blocks) — R4-proven
  const int flat = blockIdx.x + 16 * blockIdx.y + 256 * blockIdx.z;
  const int xcd = flat & 7;
  const int slot = flat >> 3;          // 0..63 within XCD
  const int gsub = slot >> 4;          // 0..3
  int qt = slot & 15;
  if (gsub & 2) qt = 15 - qt;          // complementary pairing on each CU
  const int g = gsub * 8 + xcd;        // (b,h) group 0..31
  const int h = g & 15;
  const int b = g >> 4;
  const int i0 = qt * 64;

  const int swz = ((t & 7) ^ ((t >> 3) & 7)) * 8;  // staging source-chunk swizzle
  const int c0 = (qd ^ (lr & 7)) * 8;              // fragment-read chunk offsets
  const int c1 = c0 ^ 32;
  const int row8 = t >> 3;

  const int jmax = min(K_, i0 + 64 + M_);

  // tiled pos fragment base: group for tile tt, frag pc is g0 + 4*tt + pc.
  // g0 = 63 - i0/16 - w >= 0; max group used (incl. one-past-end prefetch) <= 135.
  const int g0 = 63 - (i0 >> 4) - w;
  const u16* pb0 = posT + (size_t)b * 139264 + qd * 128 + lr * 8;

  // ---- pre-loop staging: Q -> Ks[1], tile0 K -> Ks[0], V -> Vt[0] ----
#pragma unroll
  for (int rd = 0; rd < 2; rd++)
    gll16(qb + (size_t)(b * S_ + i0 + rd * 32 + row8) * 1024 + h * 64 + swz,
          &Ks[1][0] + rd * 2048 + w * 512);
#pragma unroll
  for (int rd = 0; rd < 2; rd++) {
    gll16(kb + (size_t)(b * K_ + rd * 32 + row8) * 1024 + h * 64 + swz,
          &Ks[0][0] + rd * 2048 + w * 512);
    gll16(vbT + (size_t)((b * H_ + h) * 64 + rd * 32 + row8) * K_ + swz,
          &Vt[0][0] + rd * 2048 + w * 512);
  }
  // preload pos fragments for tile 0 (registers, coalesced)
  short8 pg0[5], pg1[5];
  {
    const u16* pp = pb0 + (size_t)g0 * 1024;
#pragma unroll
    for (int pc = 0; pc < 5; pc++) {
      pg0[pc] = *(const short8*)(pp + pc * 1024);
      pg1[pc] = *(const short8*)(pp + pc * 1024 + 512);
    }
  }
  __syncthreads();
  const short8 aQ0 = *(const short8*)&Ks[1][(w * 16 + lr) * 64 + c0];
  const short8 aQ1 = *(const short8*)&Ks[1][(w * 16 + lr) * 64 + c1];

  f32x4 accO[4];
#pragma unroll
  for (int d = 0; d < 4; d++) accO[d] = (f32x4){0.f, 0.f, 0.f, 0.f};
  float lsum[4];
#pragma unroll
  for (int r = 0; r < 4; r++) lsum[r] = 0.f;

  // pipeline state: P fragments of the previous tile + its V buffer index
  short8 aPp0 = {}, aPp1 = {};
  int vprev = 0, vcur = 0;

  for (int j0 = 0, tt = 0; j0 < jmax; j0 += 64, tt++) {
    __syncthreads();
    const int vnxt = (vcur == 2) ? 0 : vcur + 1;
    if (j0 + 64 < jmax) {
      const int knxt = (tt + 1) & 1;
#pragma unroll
      for (int rd = 0; rd < 2; rd++) {
        gll16(kb + (size_t)(b * K_ + j0 + 64 + rd * 32 + row8) * 1024 + h * 64 + swz,
              &Ks[knxt][0] + rd * 2048 + w * 512);
        gll16(vbT + (size_t)((b * H_ + h) * 64 + rd * 32 + row8) * K_ + j0 + 64 + swz,
              &Vt[vnxt][0] + rd * 2048 + w * 512);
      }
    }

    __builtin_amdgcn_s_setprio(1);
    // ---- Q @ pos-band^T: register-only MFMAs (operands prefetched last tile) ----
    f32x4 zp[5];
#pragma unroll
    for (int pc = 0; pc < 5; pc++) {
      f32x4 z = {0.f, 0.f, 0.f, 0.f};
      z = mfma16(aQ0, pg0[pc], z);
      zp[pc] = mfma16(aQ1, pg1[pc], z);
    }

    // ---- QK^T: 16 rows x 64 keys (Ks[tt&1]) ----
    f32x4 sqk[4];
#pragma unroll
    for (int kc = 0; kc < 4; kc++) {
      const short8 bK0 = *(const short8*)&Ks[tt & 1][(kc * 16 + lr) * 64 + c0];
      const short8 bK1 = *(const short8*)&Ks[tt & 1][(kc * 16 + lr) * 64 + c1];
      f32x4 z = {0.f, 0.f, 0.f, 0.f};
      z = mfma16(aQ0, bK0, z);
      sqk[kc] = mfma16(aQ1, bK1, z);
    }

    // ---- PV(t-1): overlaps the softmax VALU phase below (MFMA + LDS pipes) ----
    if (tt > 0) {
#pragma unroll
      for (int d2 = 0; d2 < 4; d2++) {
        const short8 bV0 = *(const short8*)&Vt[vprev][(d2 * 16 + lr) * 64 + c0];
        const short8 bV1 = *(const short8*)&Vt[vprev][(d2 * 16 + lr) * 64 + c1];
        accO[d2] = mfma16(aPp0, bV0, accO[d2]);
        accO[d2] = mfma16(aPp1, bV1, accO[d2]);
      }
    }
    __builtin_amdgcn_s_setprio(0);

    // ---- prefetch next tile's pos fragments (groups bounded <= 135) ----
    {
      const u16* pn = pb0 + (size_t)(g0 + 4 * (tt + 1)) * 1024;
#pragma unroll
      for (int pc = 0; pc < 5; pc++) {
        pg0[pc] = *(const short8*)(pn + pc * 1024);
        pg1[pc] = *(const short8*)(pn + pc * 1024 + 512);
      }
    }

    // ---- shuffle-based skew gather + max-free softmax ----
    const bool tail = (j0 + 63 > i0 + w * 16 + M_);  // wave-uniform
    float p[4][4];
#pragma unroll
    for (int r = 0; r < 4; r++) {
      const int iL = qd * 4 + r;
      const int d = 15 + lr - iL;                    // [0,30]
      const int srcl = qd * 16 + (d & 15);
      const bool hi = (d >> 4) & 1;
      float g0s = __shfl(zp[0][r], srcl, 64);
      float g1s = __shfl(zp[1][r], srcl, 64);
      float g2s = __shfl(zp[2][r], srcl, 64);
      float g3s = __shfl(zp[3][r], srcl, 64);
      float g4s = __shfl(zp[4][r], srcl, 64);
      float s0 = sqk[0][r] + (hi ? g1s : g0s);
      float s1 = sqk[1][r] + (hi ? g2s : g1s);
      float s2 = sqk[2][r] + (hi ? g3s : g2s);
      float s3 = sqk[3][r] + (hi ? g4s : g3s);
      if (tail) {
        const int key = j0 + lr, lim = i0 + w * 16 + iL + M_;
        if (key      > lim) s0 = NEG_BIG;
        if (key + 16 > lim) s1 = NEG_BIG;
        if (key + 32 > lim) s2 = NEG_BIG;
        if (key + 48 > lim) s3 = NEG_BIG;
      }
      p[0][r] = __expf(s0);
      p[1][r] = __expf(s1);
      p[2][r] = __expf(s2);
      p[3][r] = __expf(s3);
      lsum[r] += p[0][r] + p[1][r] + p[2][r] + p[3][r];
    }

    // ---- P -> wave-private LDS (XOR chunk swizzle) -> A-fragments for NEXT iter ----
#pragma unroll
    for (int r = 0; r < 4; r++) {
      const int row = qd * 4 + r;
      const int cbase = row * 64;
      const int rx = row & 7;
      const int lo = lr & 7, hi8 = lr >> 3;
#pragma unroll
      for (int kc = 0; kc < 4; kc++)
        Pt[w][cbase + ((((kc << 1) | hi8) ^ rx) << 3) + lo] = f2bf(p[kc][r]);
    }
    __asm__ volatile("s_waitcnt lgkmcnt(0)" ::: "memory");
    aPp0 = *(const short8*)&Pt[w][lr * 64 + ((qd ^ (lr & 7)) << 3)];
    aPp1 = *(const short8*)&Pt[w][lr * 64 + (((qd + 4) ^ (lr & 7)) << 3)];

    vprev = vcur;
    vcur = vnxt;
  }

  // ---- drain the pipeline: PV for the last tile ----
#pragma unroll
  for (int d2 = 0; d2 < 4; d2++) {
    const short8 bV0 = *(const short8*)&Vt[vprev][(d2 * 16 + lr) * 64 + c0];
    const short8 bV1 = *(const short8*)&Vt[vprev][(d2 * 16 + lr) * 64 + c1];
    accO[d2] = mfma16(aPp0, bV0, accO[d2]);
    accO[d2] = mfma16(aPp1, bV1, accO[d2]);
  }

  // ---- epilogue: one 16-lane reduction of lsum, then normalize ----
  float inv[4];
#pragma unroll
  for (int r = 0; r < 4; r++) {
#pragma unroll
    for (int msk = 1; msk < 16; msk <<= 1) lsum[r] += __shfl_xor(lsum[r], msk, 64);
    inv[r] = 1.0f / lsum[r];
  }
#pragma unroll
  for (int d2 = 0; d2 < 4; d2++)
#pragma unroll
    for (int r = 0; r < 4; r++) {
      const int iG = i0 + w * 16 + qd * 4 + r;
      ab[(size_t)(b * S_ + iG) * 1024 + h * 64 + d2 * 16 + lr] = f2bf(accO[d2][r] * inv[r]);
    }
}

// ---------------- launch ----------------
extern "C" void kernel_launch(void* const* d_in, const int* in_sizes, int n_in,
                              void* d_out, int out_size, void* d_ws, size_t ws_size,
                              hipStream_t stream) {
  const float* hidden = (const float*)d_in[0];
  const float* pos    = (const float*)d_in[1];
  const float* memory = (const float*)d_in[2];
  // d_in[3] = mask (bool) — causality applied analytically, unused
  const float* Wq = (const float*)d_in[4];
  const float* Wk = (const float*)d_in[5];
  const float* Wv = (const float*)d_in[6];
  const float* Wo = (const float*)d_in[7];
  const float* gamma = (const float*)d_in[8];
  const float* beta  = (const float*)d_in[9];

  char* ws = (char*)d_ws;
  u16* cln  = (u16*)(ws);               // 8 MB
  u16* qb   = (u16*)(ws + 8388608);     // 4 MB (pre-scaled 1/32)
  u16* kb   = (u16*)(ws + 12582912);    // 8 MB
  u16* vbT  = (u16*)(ws + 20971520);    // 8 MB
  u16* ab   = (u16*)(ws + 29360128);    // 4 MB
  u16* WqT  = (u16*)(ws + 33554432);    // 4 x 2 MB contiguous (WqT|WkT|WvT|WoT)
  u16* WkT  = WqT + 1048576;
  u16* WvT  = WkT + 1048576;
  u16* WoT  = WvT + 1048576;
  u16* posT = (u16*)(ws + 41943040);    // 0.54 MB tiled pos

  prep_kernel<<<dim3(5256), 256, 0, stream>>>(
      hidden, memory, gamma, beta, cln,
      Wq, Wk, Wv, Wo, WqT, WkT, WvT, WoT, pos, posT);
  gemm_qkv_kernel<<<dim3(24, 32), 256, 0, stream>>>(cln, WqT, qb, kb, vbT);
  attn_kernel<<<dim3(S_ / 64, H_, B_), 256, 0, stream>>>(qb, kb, vbT, posT, ab);
  out_gemm_kernel<<<dim3(16, 16), 256, 0, stream>>>(ab, WoT, cln, (float*)d_out);
}

// Round 8
// 202.449 us; speedup vs baseline: 1.2965x; 1.0147x over previous
//
#include <hip/hip_runtime.h>
#include <hip/hip_bf16.h>

// Problem constants (B,S,M,D,H,DH = 2,1024,1024,1024,16,64)
#define B_ 2
#define S_ 1024
#define M_ 1024
#define D_ 1024
#define H_ 16
#define DH_ 64
#define K_ 2048
#define R_ 4095

// finite stand-in for -inf (avoids inf arithmetic under fast-math)
#define NEG_BIG (-1e30f)

typedef unsigned short u16;
typedef short short8 __attribute__((ext_vector_type(8)));
typedef float f32x4 __attribute__((ext_vector_type(4)));

__device__ __forceinline__ u16 f2bf(float f) {
  __hip_bfloat16 h = __float2bfloat16(f);
  return *reinterpret_cast<u16*>(&h);
}
__device__ __forceinline__ float bf2f(u16 u) {
  __hip_bfloat16 h;
  *reinterpret_cast<u16*>(&h) = u;
  return __bfloat162float(h);
}

// async global->LDS, 16B per lane; LDS dest = wave-uniform base + lane*16
__device__ __forceinline__ void gll16(const void* g, const void* l) {
  __builtin_amdgcn_global_load_lds(
      (const __attribute__((address_space(1))) unsigned int*)g,
      (__attribute__((address_space(3))) unsigned int*)l, 16, 0, 0);
}

__device__ __forceinline__ f32x4 mfma16(short8 a, short8 b, f32x4 c) {
  return __builtin_amdgcn_mfma_f32_16x16x32_bf16(a, b, c, 0, 0, 0);
}

// ---------------- fused prep: LN(concat) + 4x weight transpose + pos tiled cvt ----------
// posT layout: [b][g<144][oct<8][r<16][j<8] bf16 (136 groups written, 8 pad groups
// readable-garbage for the one-phase-ahead prefetch), so an attn pos-fragment load
// (rows g*16+lr, cols oct*8..+8) is ONE contiguous 1KB wave transaction.
__global__ __launch_bounds__(256) void prep_kernel(
    const float* __restrict__ hidden, const float* __restrict__ memory,
    const float* __restrict__ gamma, const float* __restrict__ beta,
    u16* __restrict__ cln,
    const float* __restrict__ W0, const float* __restrict__ W1,
    const float* __restrict__ W2, const float* __restrict__ W3,
    u16* __restrict__ O0, u16* __restrict__ O1,
    u16* __restrict__ O2, u16* __restrict__ O3,
    const float* __restrict__ pos, u16* __restrict__ posT) {
  __shared__ u16 tile[64][66];
  __shared__ float red[8];
  const int bx = blockIdx.x;
  const int t = threadIdx.x;

  if (bx < 4096) {  // LayerNorm row
    const int b = bx >> 11;
    const int idx = bx & (K_ - 1);
    const float* src = (idx < M_)
        ? memory + (size_t)(b * M_ + idx) * D_
        : hidden + (size_t)(b * S_ + (idx - M_)) * D_;
    const int lane = t & 63, w = t >> 6;
    float4 rv = ((const float4*)src)[t];
    float s = rv.x + rv.y + rv.z + rv.w;
    float ss = rv.x * rv.x + rv.y * rv.y + rv.z * rv.z + rv.w * rv.w;
#pragma unroll
    for (int m = 1; m < 64; m <<= 1) {
      s += __shfl_xor(s, m, 64);
      ss += __shfl_xor(ss, m, 64);
    }
    if (lane == 0) { red[w] = s; red[4 + w] = ss; }
    __syncthreads();
    s = red[0] + red[1] + red[2] + red[3];
    ss = red[4] + red[5] + red[6] + red[7];
    const float mu = s * (1.0f / D_);
    const float var = ss * (1.0f / D_) - mu * mu;
    const float rstd = rsqrtf(var + 1e-5f);
    float4 gv = ((const float4*)gamma)[t];
    float4 bv = ((const float4*)beta)[t];
    ushort4 ov;
    ov.x = f2bf((rv.x - mu) * rstd * gv.x + bv.x);
    ov.y = f2bf((rv.y - mu) * rstd * gv.y + bv.y);
    ov.z = f2bf((rv.z - mu) * rstd * gv.z + bv.z);
    ov.w = f2bf((rv.w - mu) * rstd * gv.w + bv.w);
    ((ushort4*)(cln + (size_t)bx * D_))[t] = ov;
    return;
  }
  if (bx < 5120) {  // weight transpose slab
    const int z = (bx - 4096) >> 8;
    const int rem = (bx - 4096) & 255;
    const float* in; u16* out;
    switch (z) {
      case 0:  in = W0; out = O0; break;
      case 1:  in = W1; out = O1; break;
      case 2:  in = W2; out = O2; break;
      default: in = W3; out = O3; break;
    }
    const int tx = t & 63, ty = t >> 6;
    const int k0 = (rem & 15) * 64, n0 = (rem >> 4) * 64;
#pragma unroll
    for (int i = ty; i < 64; i += 4)
      tile[i][tx] = f2bf(in[(size_t)(k0 + i) * D_ + n0 + tx]);
    __syncthreads();
#pragma unroll
    for (int i = ty; i < 64; i += 4)
      out[(size_t)(n0 + i) * D_ + k0 + tx] = tile[tx][i];
    return;
  }
  // pos f32 -> bf16, tiled: u enumerates (b, g, r, oct); 136 groups of 16 rows per batch
  {
    const int u = (bx - 5120) * 256 + t;    // [0, 34816)
    const int oct = u & 7;
    const int r = (u >> 3) & 15;
    const int g = (u >> 7) % 136;
    const int b = u / 17408;                // 136*128
    const int row = g * 16 + r;             // <= 2175 < R_ (always in-bounds)
    const float* s = pos + ((size_t)b * R_ + row) * 64 + oct * 8;
    float4 v0 = ((const float4*)s)[0];
    float4 v1 = ((const float4*)s)[1];
    ushort4 oA, oB;
    oA.x = f2bf(v0.x); oA.y = f2bf(v0.y); oA.z = f2bf(v0.z); oA.w = f2bf(v0.w);
    oB.x = f2bf(v1.x); oB.y = f2bf(v1.y); oB.z = f2bf(v1.z); oB.w = f2bf(v1.w);
    u16* d = posT + (size_t)(b * 144 + g) * 1024 + oct * 128 + r * 8;  // 144-group stride
    ((ushort4*)d)[0] = oA;
    ((ushort4*)d)[1] = oB;
  }
}

// row r of the "hidden slice" view -> row of c_ln
__device__ __forceinline__ int maprow_hidden(int r) {
  return r + ((r >> 10) << 10) + M_;
}

// ---------------- QKV GEMM: BK=64, XOR-swizzled staging, 3 blocks/CU ----------------
__global__ __launch_bounds__(256, 3) void gemm_qkv_kernel(
    const u16* __restrict__ A, const u16* __restrict__ Bt,
    u16* __restrict__ qb, u16* __restrict__ kb, u16* __restrict__ vbT) {
  __shared__ __align__(16) u16 As[128 * 64];   // 16 KB
  __shared__ __align__(16) u16 Bs[128 * 64];   // 16 KB
  const int t = threadIdx.x;
  const int lane = t & 63, w = t >> 6;
  const int wm = w >> 1, wn = w & 1;
  const int qd = lane >> 4, lr = lane & 15;
  const int m0 = blockIdx.y * 128, n0 = blockIdx.x * 128;
  if (n0 < 1024 && !(m0 & 1024)) return;   // dead Q tiles (memory rows)

  const int swz = ((t & 7) ^ ((t >> 3) & 7)) * 8;  // source-chunk swizzle
  const int c0 = (qd ^ (lr & 7)) * 8;
  const int c1 = c0 ^ 32;
  const int row8 = (t >> 3) & 7;

  f32x4 acc[4][4];
#pragma unroll
  for (int mt = 0; mt < 4; mt++)
#pragma unroll
    for (int nt = 0; nt < 4; nt++) acc[mt][nt] = (f32x4){0.f, 0.f, 0.f, 0.f};

  for (int kt = 0; kt < 1024; kt += 64) {
#pragma unroll
    for (int p = 0; p < 4; p++) {
      const int ra = w * 32 + p * 8 + row8;
      gll16(A + (size_t)(m0 + ra) * 1024 + kt + swz, As + (w * 32 + p * 8) * 64);
      gll16(Bt + (size_t)(n0 + ra) * 1024 + kt + swz, Bs + (w * 32 + p * 8) * 64);
    }
    __syncthreads();
    short8 a0[4], a1[4], b0[4], b1[4];
#pragma unroll
    for (int mt = 0; mt < 4; mt++) {
      a0[mt] = *(const short8*)&As[(wm * 64 + mt * 16 + lr) * 64 + c0];
      a1[mt] = *(const short8*)&As[(wm * 64 + mt * 16 + lr) * 64 + c1];
    }
#pragma unroll
    for (int nt = 0; nt < 4; nt++) {
      b0[nt] = *(const short8*)&Bs[(wn * 64 + nt * 16 + lr) * 64 + c0];
      b1[nt] = *(const short8*)&Bs[(wn * 64 + nt * 16 + lr) * 64 + c1];
    }
#pragma unroll
    for (int mt = 0; mt < 4; mt++)
#pragma unroll
      for (int nt = 0; nt < 4; nt++) {
        acc[mt][nt] = mfma16(a0[mt], b0[nt], acc[mt][nt]);
        acc[mt][nt] = mfma16(a1[mt], b1[nt], acc[mt][nt]);
      }
    __syncthreads();
  }

#pragma unroll
  for (int mt = 0; mt < 4; mt++)
#pragma unroll
    for (int nt = 0; nt < 4; nt++) {
      const int colb = n0 + wn * 64 + nt * 16;
      const int rowb = m0 + wm * 64 + mt * 16 + qd * 4;
      if (colb < 1024) {                               // Q (pre-scaled 1/32)
        const int qrow = ((rowb >> 11) << 10) | (rowb & 1023);
#pragma unroll
        for (int r = 0; r < 4; r++)
          qb[(size_t)(qrow + r) * 1024 + colb + lr] = f2bf(acc[mt][nt][r] * 0.03125f);
      } else if (colb < 2048) {                        // K row-major
        const int key = rowb & (K_ - 1);
        const int bq = rowb >> 11;
#pragma unroll
        for (int r = 0; r < 4; r++)
          kb[(size_t)(bq * K_ + key + r) * 1024 + (colb - 1024) + lr] = f2bf(acc[mt][nt][r]);
      } else {                                         // V transposed [b*H+h][dh][key]
        const int nn = colb - 2048 + lr;
        const int bh = ((rowb >> 11) << 4) | (nn >> 6);
        const int dh = nn & 63;
        const int key = rowb & (K_ - 1);
        ushort4 pk;
        pk.x = f2bf(acc[mt][nt][0]);
        pk.y = f2bf(acc[mt][nt][1]);
        pk.z = f2bf(acc[mt][nt][2]);
        pk.w = f2bf(acc[mt][nt][3]);
        *(ushort4*)&vbT[((size_t)bh * 64 + dh) * K_ + key] = pk;
      }
    }
}

// ---------------- out GEMM: 128x64 tiles (256 blocks), f32 out + LN residual ----------------
__global__ __launch_bounds__(256, 2) void out_gemm_kernel(
    const u16* __restrict__ A, const u16* __restrict__ Bt,
    const u16* __restrict__ resid, float* __restrict__ Cf) {
  __shared__ __align__(16) u16 As[128 * 32];
  __shared__ __align__(16) u16 Bs[64 * 32];
  const int t = threadIdx.x;
  const int lane = t & 63, w = t >> 6;
  const int wm = w >> 1, wn = w & 1;
  const int qd = lane >> 4, lr = lane & 15;
  const int m0 = blockIdx.y * 128, n0 = blockIdx.x * 64;

  const u16* Ag0 = A + (size_t)(m0 + (t >> 2)) * 1024 + (t & 3) * 8;
  const u16* Ag1 = Ag0 + (size_t)64 * 1024;
  const u16* Bg0 = Bt + (size_t)(n0 + (t >> 2)) * 1024 + (t & 3) * 8;

  f32x4 acc[4][2];
#pragma unroll
  for (int mt = 0; mt < 4; mt++)
#pragma unroll
    for (int nt = 0; nt < 2; nt++) acc[mt][nt] = (f32x4){0.f, 0.f, 0.f, 0.f};

  for (int kt = 0; kt < 1024; kt += 32) {
    gll16(Ag0 + kt, As + w * 512);
    gll16(Ag1 + kt, As + 2048 + w * 512);
    gll16(Bg0 + kt, Bs + w * 512);
    __syncthreads();
    short8 af[4], bfr[2];
#pragma unroll
    for (int mt = 0; mt < 4; mt++)
      af[mt] = *(const short8*)&As[(wm * 64 + mt * 16 + lr) * 32 + qd * 8];
#pragma unroll
    for (int nt = 0; nt < 2; nt++)
      bfr[nt] = *(const short8*)&Bs[(wn * 32 + nt * 16 + lr) * 32 + qd * 8];
#pragma unroll
    for (int mt = 0; mt < 4; mt++)
#pragma unroll
      for (int nt = 0; nt < 2; nt++)
        acc[mt][nt] = mfma16(af[mt], bfr[nt], acc[mt][nt]);
    __syncthreads();
  }

#pragma unroll
  for (int mt = 0; mt < 4; mt++)
#pragma unroll
    for (int nt = 0; nt < 2; nt++)
#pragma unroll
      for (int r = 0; r < 4; r++) {
        const int row = m0 + wm * 64 + mt * 16 + qd * 4 + r;
        const int col = n0 + wn * 32 + nt * 16 + lr;
        float v = acc[mt][nt][r] + bf2f(resid[(size_t)maprow_hidden(row) * 1024 + col]);
        Cf[(size_t)row * 1024 + col] = v;
      }
}

// ---------------- attention: KVBLK=128 (two 64-key sub-tiles per barrier phase) --------
// R4 memory behavior kept verbatim (XCD-grouped remap, FETCH 12 MB proven; tiled posT
// in registers). One barrier per 128 keys halves sync/drain overhead and doubles the
// scheduler window. Ks/Vt double-buffered at phase granularity; Pt single-buffered
// (wave-private, in-order DS). LDS 72 KB, 2 blocks/CU. grid (16, H, B).
__global__ __launch_bounds__(256, 2) void attn_kernel(
    const u16* __restrict__ qb, const u16* __restrict__ kb,
    const u16* __restrict__ vbT, const u16* __restrict__ posT,
    u16* __restrict__ ab) {
  __shared__ __align__(16) u16 Ks[2][2][64 * 64];   // 32 KB (Ks[1][0] aliases Q pre-loop)
  __shared__ __align__(16) u16 Vt[2][2][64 * 64];   // 32 KB  [dh][key]
  __shared__ __align__(16) u16 Pt[4][16 * 64];      // 8 KB wave-private (XOR-swizzled)

  const int t = threadIdx.x;
  const int lane = t & 63, w = t >> 6;
  const int qd = lane >> 4, lr = lane & 15;

  // XCD-grouping remap (bijective on 512 blocks) — R4-proven
  const int flat = blockIdx.x + 16 * blockIdx.y + 256 * blockIdx.z;
  const int xcd = flat & 7;
  const int slot = flat >> 3;          // 0..63 within XCD
  const int gsub = slot >> 4;          // 0..3
  int qt = slot & 15;
  if (gsub & 2) qt = 15 - qt;          // complementary pairing on each CU
  const int g = gsub * 8 + xcd;        // (b,h) group 0..31
  const int h = g & 15;
  const int b = g >> 4;
  const int i0 = qt * 64;

  const int swz = ((t & 7) ^ ((t >> 3) & 7)) * 8;  // staging source-chunk swizzle
  const int c0 = (qd ^ (lr & 7)) * 8;              // fragment-read chunk offsets
  const int c1 = c0 ^ 32;
  const int row8 = t >> 3;

  const int jmax = min(K_, i0 + 64 + M_);

  // tiled pos fragment base: group for 64-key sub tt, frag pc is g0 + 4*tt + pc.
  // One-phase-ahead prefetch reaches group <= 143 -> 144-group posT stride.
  const int g0 = 63 - (i0 >> 4) - w;
  const u16* pb0 = posT + (size_t)b * 147456 + qd * 128 + lr * 8;

  // ---- pre-loop staging: Q -> Ks[1][0]; phase0 K/V (both subs) -> buf0 ----
#pragma unroll
  for (int rd = 0; rd < 2; rd++)
    gll16(qb + (size_t)(b * S_ + i0 + rd * 32 + row8) * 1024 + h * 64 + swz,
          &Ks[1][0][0] + rd * 2048 + w * 512);
#pragma unroll
  for (int sb = 0; sb < 2; sb++)
#pragma unroll
    for (int rd = 0; rd < 2; rd++) {
      gll16(kb + (size_t)(b * K_ + sb * 64 + rd * 32 + row8) * 1024 + h * 64 + swz,
            &Ks[0][sb][0] + rd * 2048 + w * 512);
      gll16(vbT + (size_t)((b * H_ + h) * 64 + rd * 32 + row8) * K_ + sb * 64 + swz,
            &Vt[0][sb][0] + rd * 2048 + w * 512);
    }
  // preload pos fragments for phase0 subs (registers, coalesced)
  short8 pgA0[5], pgA1[5], pgB0[5], pgB1[5];
  {
    const u16* pp = pb0 + (size_t)g0 * 1024;
#pragma unroll
    for (int pc = 0; pc < 5; pc++) {
      pgA0[pc] = *(const short8*)(pp + pc * 1024);
      pgA1[pc] = *(const short8*)(pp + pc * 1024 + 512);
    }
    const u16* p2 = pb0 + (size_t)(g0 + 4) * 1024;
#pragma unroll
    for (int pc = 0; pc < 5; pc++) {
      pgB0[pc] = *(const short8*)(p2 + pc * 1024);
      pgB1[pc] = *(const short8*)(p2 + pc * 1024 + 512);
    }
  }
  __syncthreads();
  const short8 aQ0 = *(const short8*)&Ks[1][0][(w * 16 + lr) * 64 + c0];
  const short8 aQ1 = *(const short8*)&Ks[1][0][(w * 16 + lr) * 64 + c1];

  f32x4 accO[4];
#pragma unroll
  for (int d = 0; d < 4; d++) accO[d] = (f32x4){0.f, 0.f, 0.f, 0.f};
  float lsum[4];
#pragma unroll
  for (int r = 0; r < 4; r++) lsum[r] = 0.f;

  for (int j0 = 0, ph = 0; j0 < jmax; j0 += 128, ph++) {
    __syncthreads();
    const int cb = ph & 1;
    const int nb = cb ^ 1;
    const int j0n = j0 + 128;
    // ---- stage phase+1 (per-sub guard; valid subs are fully in-bounds) ----
#pragma unroll
    for (int sb = 0; sb < 2; sb++)
      if (j0n + sb * 64 < jmax) {
#pragma unroll
        for (int rd = 0; rd < 2; rd++) {
          gll16(kb + (size_t)(b * K_ + j0n + sb * 64 + rd * 32 + row8) * 1024 + h * 64 + swz,
                &Ks[nb][sb][0] + rd * 2048 + w * 512);
          gll16(vbT + (size_t)((b * H_ + h) * 64 + rd * 32 + row8) * K_ + j0n + sb * 64 + swz,
                &Vt[nb][sb][0] + rd * 2048 + w * 512);
        }
      }

    // ================= SUB 0 (keys j0 .. j0+63) =================
    {
      __builtin_amdgcn_s_setprio(1);
      f32x4 zp[5];
#pragma unroll
      for (int pc = 0; pc < 5; pc++) {
        f32x4 z = {0.f, 0.f, 0.f, 0.f};
        z = mfma16(aQ0, pgA0[pc], z);
        zp[pc] = mfma16(aQ1, pgA1[pc], z);
      }
      f32x4 sqk[4];
#pragma unroll
      for (int kc = 0; kc < 4; kc++) {
        const short8 bK0 = *(const short8*)&Ks[cb][0][(kc * 16 + lr) * 64 + c0];
        const short8 bK1 = *(const short8*)&Ks[cb][0][(kc * 16 + lr) * 64 + c1];
        f32x4 z = {0.f, 0.f, 0.f, 0.f};
        z = mfma16(aQ0, bK0, z);
        sqk[kc] = mfma16(aQ1, bK1, z);
      }
      __builtin_amdgcn_s_setprio(0);
      // prefetch pgA for next phase's sub0 (tt = 2*ph+2)
      {
        const u16* pn = pb0 + (size_t)(g0 + 4 * (2 * ph + 2)) * 1024;
#pragma unroll
        for (int pc = 0; pc < 5; pc++) {
          pgA0[pc] = *(const short8*)(pn + pc * 1024);
          pgA1[pc] = *(const short8*)(pn + pc * 1024 + 512);
        }
      }
      // shuffle-based skew gather + max-free softmax
      const bool tail = (j0 + 63 > i0 + w * 16 + M_);
      float p[4][4];
#pragma unroll
      for (int r = 0; r < 4; r++) {
        const int iL = qd * 4 + r;
        const int d = 15 + lr - iL;
        const int srcl = qd * 16 + (d & 15);
        const bool hi = (d >> 4) & 1;
        float g0s = __shfl(zp[0][r], srcl, 64);
        float g1s = __shfl(zp[1][r], srcl, 64);
        float g2s = __shfl(zp[2][r], srcl, 64);
        float g3s = __shfl(zp[3][r], srcl, 64);
        float g4s = __shfl(zp[4][r], srcl, 64);
        float s0 = sqk[0][r] + (hi ? g1s : g0s);
        float s1 = sqk[1][r] + (hi ? g2s : g1s);
        float s2 = sqk[2][r] + (hi ? g3s : g2s);
        float s3 = sqk[3][r] + (hi ? g4s : g3s);
        if (tail) {
          const int key = j0 + lr, lim = i0 + w * 16 + iL + M_;
          if (key      > lim) s0 = NEG_BIG;
          if (key + 16 > lim) s1 = NEG_BIG;
          if (key + 32 > lim) s2 = NEG_BIG;
          if (key + 48 > lim) s3 = NEG_BIG;
        }
        p[0][r] = __expf(s0);
        p[1][r] = __expf(s1);
        p[2][r] = __expf(s2);
        p[3][r] = __expf(s3);
        lsum[r] += p[0][r] + p[1][r] + p[2][r] + p[3][r];
      }
      // P -> wave-private LDS (XOR chunk swizzle) -> A-fragments
#pragma unroll
      for (int r = 0; r < 4; r++) {
        const int row = qd * 4 + r;
        const int cbase = row * 64;
        const int rx = row & 7;
        const int lo = lr & 7, hi8 = lr >> 3;
#pragma unroll
        for (int kc = 0; kc < 4; kc++)
          Pt[w][cbase + ((((kc << 1) | hi8) ^ rx) << 3) + lo] = f2bf(p[kc][r]);
      }
      __asm__ volatile("s_waitcnt lgkmcnt(0)" ::: "memory");
      const short8 aP0 = *(const short8*)&Pt[w][lr * 64 + ((qd ^ (lr & 7)) << 3)];
      const short8 aP1 = *(const short8*)&Pt[w][lr * 64 + (((qd + 4) ^ (lr & 7)) << 3)];
      // P @ V
      __builtin_amdgcn_s_setprio(1);
#pragma unroll
      for (int d2 = 0; d2 < 4; d2++) {
        const short8 bV0 = *(const short8*)&Vt[cb][0][(d2 * 16 + lr) * 64 + c0];
        const short8 bV1 = *(const short8*)&Vt[cb][0][(d2 * 16 + lr) * 64 + c1];
        accO[d2] = mfma16(aP0, bV0, accO[d2]);
        accO[d2] = mfma16(aP1, bV1, accO[d2]);
      }
      __builtin_amdgcn_s_setprio(0);
    }

    // ================= SUB 1 (keys j0+64 .. j0+127) =================
    if (j0 + 64 < jmax) {
      const int j1 = j0 + 64;
      __builtin_amdgcn_s_setprio(1);
      f32x4 zp[5];
#pragma unroll
      for (int pc = 0; pc < 5; pc++) {
        f32x4 z = {0.f, 0.f, 0.f, 0.f};
        z = mfma16(aQ0, pgB0[pc], z);
        zp[pc] = mfma16(aQ1, pgB1[pc], z);
      }
      f32x4 sqk[4];
#pragma unroll
      for (int kc = 0; kc < 4; kc++) {
        const short8 bK0 = *(const short8*)&Ks[cb][1][(kc * 16 + lr) * 64 + c0];
        const short8 bK1 = *(const short8*)&Ks[cb][1][(kc * 16 + lr) * 64 + c1];
        f32x4 z = {0.f, 0.f, 0.f, 0.f};
        z = mfma16(aQ0, bK0, z);
        sqk[kc] = mfma16(aQ1, bK1, z);
      }
      __builtin_amdgcn_s_setprio(0);
      // prefetch pgB for next phase's sub1 (tt = 2*ph+3)
      {
        const u16* pn = pb0 + (size_t)(g0 + 4 * (2 * ph + 3)) * 1024;
#pragma unroll
        for (int pc = 0; pc < 5; pc++) {
          pgB0[pc] = *(const short8*)(pn + pc * 1024);
          pgB1[pc] = *(const short8*)(pn + pc * 1024 + 512);
        }
      }
      const bool tail = (j1 + 63 > i0 + w * 16 + M_);
      float p[4][4];
#pragma unroll
      for (int r = 0; r < 4; r++) {
        const int iL = qd * 4 + r;
        const int d = 15 + lr - iL;
        const int srcl = qd * 16 + (d & 15);
        const bool hi = (d >> 4) & 1;
        float g0s = __shfl(zp[0][r], srcl, 64);
        float g1s = __shfl(zp[1][r], srcl, 64);
        float g2s = __shfl(zp[2][r], srcl, 64);
        float g3s = __shfl(zp[3][r], srcl, 64);
        float g4s = __shfl(zp[4][r], srcl, 64);
        float s0 = sqk[0][r] + (hi ? g1s : g0s);
        float s1 = sqk[1][r] + (hi ? g2s : g1s);
        float s2 = sqk[2][r] + (hi ? g3s : g2s);
        float s3 = sqk[3][r] + (hi ? g4s : g3s);
        if (tail) {
          const int key = j1 + lr, lim = i0 + w * 16 + iL + M_;
          if (key      > lim) s0 = NEG_BIG;
          if (key + 16 > lim) s1 = NEG_BIG;
          if (key + 32 > lim) s2 = NEG_BIG;
          if (key + 48 > lim) s3 = NEG_BIG;
        }
        p[0][r] = __expf(s0);
        p[1][r] = __expf(s1);
        p[2][r] = __expf(s2);
        p[3][r] = __expf(s3);
        lsum[r] += p[0][r] + p[1][r] + p[2][r] + p[3][r];
      }
#pragma unroll
      for (int r = 0; r < 4; r++) {
        const int row = qd * 4 + r;
        const int cbase = row * 64;
        const int rx = row & 7;
        const int lo = lr & 7, hi8 = lr >> 3;
#pragma unroll
        for (int kc = 0; kc < 4; kc++)
          Pt[w][cbase + ((((kc << 1) | hi8) ^ rx) << 3) + lo] = f2bf(p[kc][r]);
      }
      __asm__ volatile("s_waitcnt lgkmcnt(0)" ::: "memory");
      const short8 aP0 = *(const short8*)&Pt[w][lr * 64 + ((qd ^ (lr & 7)) << 3)];
      const short8 aP1 = *(const short8*)&Pt[w][lr * 64 + (((qd + 4) ^ (lr & 7)) << 3)];
      __builtin_amdgcn_s_setprio(1);
#pragma unroll
      for (int d2 = 0; d2 < 4; d2++) {
        const short8 bV0 = *(const short8*)&Vt[cb][1][(d2 * 16 + lr) * 64 + c0];
        const short8 bV1 = *(const short8*)&Vt[cb][1][(d2 * 16 + lr) * 64 + c1];
        accO[d2] = mfma16(aP0, bV0, accO[d2]);
        accO[d2] = mfma16(aP1, bV1, accO[d2]);
      }
      __builtin_amdgcn_s_setprio(0);
    }
  }

  // ---- epilogue: one 16-lane reduction of lsum, then normalize ----
  float inv[4];
#pragma unroll
  for (int r = 0; r < 4; r++) {
#pragma unroll
    for (int msk = 1; msk < 16; msk <<= 1) lsum[r] += __shfl_xor(lsum[r], msk, 64);
    inv[r] = 1.0f / lsum[r];
  }
#pragma unroll
  for (int d2 = 0; d2 < 4; d2++)
#pragma unroll
    for (int r = 0; r < 4; r++) {
      const int iG = i0 + w * 16 + qd * 4 + r;
      ab[(size_t)(b * S_ + iG) * 1024 + h * 64 + d2 * 16 + lr] = f2bf(accO[d2][r] * inv[r]);
    }
}

// ---------------- launch ----------------
extern "C" void kernel_launch(void* const* d_in, const int* in_sizes, int n_in,
                              void* d_out, int out_size, void* d_ws, size_t ws_size,
                              hipStream_t stream) {
  const float* hidden = (const float*)d_in[0];
  const float* pos    = (const float*)d_in[1];
  const float* memory = (const float*)d_in[2];
  // d_in[3] = mask (bool) — causality applied analytically, unused
  const float* Wq = (const float*)d_in[4];
  const float* Wk = (const float*)d_in[5];
  const float* Wv = (const float*)d_in[6];
  const float* Wo = (const float*)d_in[7];
  const float* gamma = (const float*)d_in[8];
  const float* beta  = (const float*)d_in[9];

  char* ws = (char*)d_ws;
  u16* cln  = (u16*)(ws);               // 8 MB
  u16* qb   = (u16*)(ws + 8388608);     // 4 MB (pre-scaled 1/32)
  u16* kb   = (u16*)(ws + 12582912);    // 8 MB
  u16* vbT  = (u16*)(ws + 20971520);    // 8 MB
  u16* ab   = (u16*)(ws + 29360128);    // 4 MB
  u16* WqT  = (u16*)(ws + 33554432);    // 4 x 2 MB contiguous (WqT|WkT|WvT|WoT)
  u16* WkT  = WqT + 1048576;
  u16* WvT  = WkT + 1048576;
  u16* WoT  = WvT + 1048576;
  u16* posT = (u16*)(ws + 41943040);    // 0.56 MB tiled pos (144-group stride)

  prep_kernel<<<dim3(5256), 256, 0, stream>>>(
      hidden, memory, gamma, beta, cln,
      Wq, Wk, Wv, Wo, WqT, WkT, WvT, WoT, pos, posT);
  gemm_qkv_kernel<<<dim3(24, 32), 256, 0, stream>>>(cln, WqT, qb, kb, vbT);
  attn_kernel<<<dim3(S_ / 64, H_, B_), 256, 0, stream>>>(qb, kb, vbT, posT, ab);
  out_gemm_kernel<<<dim3(16, 16), 256, 0, stream>>>(ab, WoT, cln, (float*)d_out);
}

// Round 9
// 202.235 us; speedup vs baseline: 1.2979x; 1.0011x over previous
//
#include <hip/hip_runtime.h>
#include <hip/hip_bf16.h>

// Problem constants (B,S,M,D,H,DH = 2,1024,1024,1024,16,64)
#define B_ 2
#define S_ 1024
#define M_ 1024
#define D_ 1024
#define H_ 16
#define DH_ 64
#define K_ 2048
#define R_ 4095

// finite stand-in for -inf (avoids inf arithmetic under fast-math)
#define NEG_BIG (-1e30f)

typedef unsigned short u16;
typedef short short8 __attribute__((ext_vector_type(8)));
typedef float f32x4 __attribute__((ext_vector_type(4)));

__device__ __forceinline__ u16 f2bf(float f) {
  __hip_bfloat16 h = __float2bfloat16(f);
  return *reinterpret_cast<u16*>(&h);
}
__device__ __forceinline__ float bf2f(u16 u) {
  __hip_bfloat16 h;
  *reinterpret_cast<u16*>(&h) = u;
  return __bfloat162float(h);
}

// async global->LDS, 16B per lane; LDS dest = wave-uniform base + lane*16
__device__ __forceinline__ void gll16(const void* g, const void* l) {
  __builtin_amdgcn_global_load_lds(
      (const __attribute__((address_space(1))) unsigned int*)g,
      (__attribute__((address_space(3))) unsigned int*)l, 16, 0, 0);
}

__device__ __forceinline__ f32x4 mfma16(short8 a, short8 b, f32x4 c) {
  return __builtin_amdgcn_mfma_f32_16x16x32_bf16(a, b, c, 0, 0, 0);
}

// ---------------- fused prep: LN(concat) + 4x weight transpose + pos tiled cvt ----------
// posT layout: [b][g<144][oct<8][r<16][j<8] bf16 (136 groups written, 8 pad groups
// readable-garbage for the one-phase-ahead prefetch), so an attn pos-fragment load
// (rows g*16+lr, cols oct*8..+8) is ONE contiguous 1KB wave transaction.
__global__ __launch_bounds__(256) void prep_kernel(
    const float* __restrict__ hidden, const float* __restrict__ memory,
    const float* __restrict__ gamma, const float* __restrict__ beta,
    u16* __restrict__ cln,
    const float* __restrict__ W0, const float* __restrict__ W1,
    const float* __restrict__ W2, const float* __restrict__ W3,
    u16* __restrict__ O0, u16* __restrict__ O1,
    u16* __restrict__ O2, u16* __restrict__ O3,
    const float* __restrict__ pos, u16* __restrict__ posT) {
  __shared__ u16 tile[64][66];
  __shared__ float red[8];
  const int bx = blockIdx.x;
  const int t = threadIdx.x;

  if (bx < 4096) {  // LayerNorm row
    const int b = bx >> 11;
    const int idx = bx & (K_ - 1);
    const float* src = (idx < M_)
        ? memory + (size_t)(b * M_ + idx) * D_
        : hidden + (size_t)(b * S_ + (idx - M_)) * D_;
    const int lane = t & 63, w = t >> 6;
    float4 rv = ((const float4*)src)[t];
    float s = rv.x + rv.y + rv.z + rv.w;
    float ss = rv.x * rv.x + rv.y * rv.y + rv.z * rv.z + rv.w * rv.w;
#pragma unroll
    for (int m = 1; m < 64; m <<= 1) {
      s += __shfl_xor(s, m, 64);
      ss += __shfl_xor(ss, m, 64);
    }
    if (lane == 0) { red[w] = s; red[4 + w] = ss; }
    __syncthreads();
    s = red[0] + red[1] + red[2] + red[3];
    ss = red[4] + red[5] + red[6] + red[7];
    const float mu = s * (1.0f / D_);
    const float var = ss * (1.0f / D_) - mu * mu;
    const float rstd = rsqrtf(var + 1e-5f);
    float4 gv = ((const float4*)gamma)[t];
    float4 bv = ((const float4*)beta)[t];
    ushort4 ov;
    ov.x = f2bf((rv.x - mu) * rstd * gv.x + bv.x);
    ov.y = f2bf((rv.y - mu) * rstd * gv.y + bv.y);
    ov.z = f2bf((rv.z - mu) * rstd * gv.z + bv.z);
    ov.w = f2bf((rv.w - mu) * rstd * gv.w + bv.w);
    ((ushort4*)(cln + (size_t)bx * D_))[t] = ov;
    return;
  }
  if (bx < 5120) {  // weight transpose slab
    const int z = (bx - 4096) >> 8;
    const int rem = (bx - 4096) & 255;
    const float* in; u16* out;
    switch (z) {
      case 0:  in = W0; out = O0; break;
      case 1:  in = W1; out = O1; break;
      case 2:  in = W2; out = O2; break;
      default: in = W3; out = O3; break;
    }
    const int tx = t & 63, ty = t >> 6;
    const int k0 = (rem & 15) * 64, n0 = (rem >> 4) * 64;
#pragma unroll
    for (int i = ty; i < 64; i += 4)
      tile[i][tx] = f2bf(in[(size_t)(k0 + i) * D_ + n0 + tx]);
    __syncthreads();
#pragma unroll
    for (int i = ty; i < 64; i += 4)
      out[(size_t)(n0 + i) * D_ + k0 + tx] = tile[tx][i];
    return;
  }
  // pos f32 -> bf16, tiled: u enumerates (b, g, r, oct); 136 groups of 16 rows per batch
  {
    const int u = (bx - 5120) * 256 + t;    // [0, 34816)
    const int oct = u & 7;
    const int r = (u >> 3) & 15;
    const int g = (u >> 7) % 136;
    const int b = u / 17408;                // 136*128
    const int row = g * 16 + r;             // <= 2175 < R_ (always in-bounds)
    const float* s = pos + ((size_t)b * R_ + row) * 64 + oct * 8;
    float4 v0 = ((const float4*)s)[0];
    float4 v1 = ((const float4*)s)[1];
    ushort4 oA, oB;
    oA.x = f2bf(v0.x); oA.y = f2bf(v0.y); oA.z = f2bf(v0.z); oA.w = f2bf(v0.w);
    oB.x = f2bf(v1.x); oB.y = f2bf(v1.y); oB.z = f2bf(v1.z); oB.w = f2bf(v1.w);
    u16* d = posT + (size_t)(b * 144 + g) * 1024 + oct * 128 + r * 8;  // 144-group stride
    ((ushort4*)d)[0] = oA;
    ((ushort4*)d)[1] = oB;
  }
}

// row r of the "hidden slice" view -> row of c_ln
__device__ __forceinline__ int maprow_hidden(int r) {
  return r + ((r >> 10) << 10) + M_;
}

// ---------------- QKV GEMM: BK=64, XOR-swizzled staging, 3 blocks/CU ----------------
__global__ __launch_bounds__(256, 3) void gemm_qkv_kernel(
    const u16* __restrict__ A, const u16* __restrict__ Bt,
    u16* __restrict__ qb, u16* __restrict__ kb, u16* __restrict__ vbT) {
  __shared__ __align__(16) u16 As[128 * 64];   // 16 KB
  __shared__ __align__(16) u16 Bs[128 * 64];   // 16 KB
  const int t = threadIdx.x;
  const int lane = t & 63, w = t >> 6;
  const int wm = w >> 1, wn = w & 1;
  const int qd = lane >> 4, lr = lane & 15;
  const int m0 = blockIdx.y * 128, n0 = blockIdx.x * 128;
  if (n0 < 1024 && !(m0 & 1024)) return;   // dead Q tiles (memory rows)

  const int swz = ((t & 7) ^ ((t >> 3) & 7)) * 8;  // source-chunk swizzle
  const int c0 = (qd ^ (lr & 7)) * 8;
  const int c1 = c0 ^ 32;
  const int row8 = (t >> 3) & 7;

  f32x4 acc[4][4];
#pragma unroll
  for (int mt = 0; mt < 4; mt++)
#pragma unroll
    for (int nt = 0; nt < 4; nt++) acc[mt][nt] = (f32x4){0.f, 0.f, 0.f, 0.f};

  for (int kt = 0; kt < 1024; kt += 64) {
#pragma unroll
    for (int p = 0; p < 4; p++) {
      const int ra = w * 32 + p * 8 + row8;
      gll16(A + (size_t)(m0 + ra) * 1024 + kt + swz, As + (w * 32 + p * 8) * 64);
      gll16(Bt + (size_t)(n0 + ra) * 1024 + kt + swz, Bs + (w * 32 + p * 8) * 64);
    }
    __syncthreads();
    short8 a0[4], a1[4], b0[4], b1[4];
#pragma unroll
    for (int mt = 0; mt < 4; mt++) {
      a0[mt] = *(const short8*)&As[(wm * 64 + mt * 16 + lr) * 64 + c0];
      a1[mt] = *(const short8*)&As[(wm * 64 + mt * 16 + lr) * 64 + c1];
    }
#pragma unroll
    for (int nt = 0; nt < 4; nt++) {
      b0[nt] = *(const short8*)&Bs[(wn * 64 + nt * 16 + lr) * 64 + c0];
      b1[nt] = *(const short8*)&Bs[(wn * 64 + nt * 16 + lr) * 64 + c1];
    }
#pragma unroll
    for (int mt = 0; mt < 4; mt++)
#pragma unroll
      for (int nt = 0; nt < 4; nt++) {
        acc[mt][nt] = mfma16(a0[mt], b0[nt], acc[mt][nt]);
        acc[mt][nt] = mfma16(a1[mt], b1[nt], acc[mt][nt]);
      }
    __syncthreads();
  }

#pragma unroll
  for (int mt = 0; mt < 4; mt++)
#pragma unroll
    for (int nt = 0; nt < 4; nt++) {
      const int colb = n0 + wn * 64 + nt * 16;
      const int rowb = m0 + wm * 64 + mt * 16 + qd * 4;
      if (colb < 1024) {                               // Q (pre-scaled 1/32)
        const int qrow = ((rowb >> 11) << 10) | (rowb & 1023);
#pragma unroll
        for (int r = 0; r < 4; r++)
          qb[(size_t)(qrow + r) * 1024 + colb + lr] = f2bf(acc[mt][nt][r] * 0.03125f);
      } else if (colb < 2048) {                        // K row-major
        const int key = rowb & (K_ - 1);
        const int bq = rowb >> 11;
#pragma unroll
        for (int r = 0; r < 4; r++)
          kb[(size_t)(bq * K_ + key + r) * 1024 + (colb - 1024) + lr] = f2bf(acc[mt][nt][r]);
      } else {                                         // V transposed [b*H+h][dh][key]
        const int nn = colb - 2048 + lr;
        const int bh = ((rowb >> 11) << 4) | (nn >> 6);
        const int dh = nn & 63;
        const int key = rowb & (K_ - 1);
        ushort4 pk;
        pk.x = f2bf(acc[mt][nt][0]);
        pk.y = f2bf(acc[mt][nt][1]);
        pk.z = f2bf(acc[mt][nt][2]);
        pk.w = f2bf(acc[mt][nt][3]);
        *(ushort4*)&vbT[((size_t)bh * 64 + dh) * K_ + key] = pk;
      }
    }
}

// ---------------- out GEMM: 128x64 tiles, BK=64, XOR-swizzled (qkv's proven pattern) ----
// Was BK=32 with 8-way LDS read conflicts (row stride 64B) + 32 barrier-pairs.
// Now: 16 K-steps, conflict-free swizzled reads, 16 MFMA/wave/step. LDS 24 KB.
__global__ __launch_bounds__(256, 2) void out_gemm_kernel(
    const u16* __restrict__ A, const u16* __restrict__ Bt,
    const u16* __restrict__ resid, float* __restrict__ Cf) {
  __shared__ __align__(16) u16 As[128 * 64];   // 16 KB
  __shared__ __align__(16) u16 Bs[64 * 64];    // 8 KB
  const int t = threadIdx.x;
  const int lane = t & 63, w = t >> 6;
  const int wm = w >> 1, wn = w & 1;
  const int qd = lane >> 4, lr = lane & 15;
  const int m0 = blockIdx.y * 128, n0 = blockIdx.x * 64;

  const int swz = ((t & 7) ^ ((t >> 3) & 7)) * 8;  // source-chunk swizzle
  const int c0 = (qd ^ (lr & 7)) * 8;              // fragment-read chunk offsets
  const int c1 = c0 ^ 32;
  const int row8 = (t >> 3) & 7;

  f32x4 acc[4][2];
#pragma unroll
  for (int mt = 0; mt < 4; mt++)
#pragma unroll
    for (int nt = 0; nt < 2; nt++) acc[mt][nt] = (f32x4){0.f, 0.f, 0.f, 0.f};

  for (int kt = 0; kt < 1024; kt += 64) {
#pragma unroll
    for (int p = 0; p < 4; p++) {   // As rows 0..127
      const int ra = w * 32 + p * 8 + row8;
      gll16(A + (size_t)(m0 + ra) * 1024 + kt + swz, As + (w * 32 + p * 8) * 64);
    }
#pragma unroll
    for (int p = 0; p < 2; p++) {   // Bs rows 0..63
      const int rb = w * 16 + p * 8 + row8;
      gll16(Bt + (size_t)(n0 + rb) * 1024 + kt + swz, Bs + (w * 16 + p * 8) * 64);
    }
    __syncthreads();
    short8 a0[4], a1[4], b0[2], b1[2];
#pragma unroll
    for (int mt = 0; mt < 4; mt++) {
      a0[mt] = *(const short8*)&As[(wm * 64 + mt * 16 + lr) * 64 + c0];
      a1[mt] = *(const short8*)&As[(wm * 64 + mt * 16 + lr) * 64 + c1];
    }
#pragma unroll
    for (int nt = 0; nt < 2; nt++) {
      b0[nt] = *(const short8*)&Bs[(wn * 32 + nt * 16 + lr) * 64 + c0];
      b1[nt] = *(const short8*)&Bs[(wn * 32 + nt * 16 + lr) * 64 + c1];
    }
#pragma unroll
    for (int mt = 0; mt < 4; mt++)
#pragma unroll
      for (int nt = 0; nt < 2; nt++) {
        acc[mt][nt] = mfma16(a0[mt], b0[nt], acc[mt][nt]);
        acc[mt][nt] = mfma16(a1[mt], b1[nt], acc[mt][nt]);
      }
    __syncthreads();
  }

#pragma unroll
  for (int mt = 0; mt < 4; mt++)
#pragma unroll
    for (int nt = 0; nt < 2; nt++)
#pragma unroll
      for (int r = 0; r < 4; r++) {
        const int row = m0 + wm * 64 + mt * 16 + qd * 4 + r;
        const int col = n0 + wn * 32 + nt * 16 + lr;
        float v = acc[mt][nt][r] + bf2f(resid[(size_t)maprow_hidden(row) * 1024 + col]);
        Cf[(size_t)row * 1024 + col] = v;
      }
}

// ---------------- attention: KVBLK=128 (two 64-key sub-tiles per barrier phase) --------
// R4 memory behavior kept verbatim (XCD-grouped remap, FETCH 12 MB proven; tiled posT
// in registers). One barrier per 128 keys halves sync/drain overhead and doubles the
// scheduler window. Ks/Vt double-buffered at phase granularity; Pt single-buffered
// (wave-private, in-order DS). LDS 72 KB, 2 blocks/CU. grid (16, H, B).
__global__ __launch_bounds__(256, 2) void attn_kernel(
    const u16* __restrict__ qb, const u16* __restrict__ kb,
    const u16* __restrict__ vbT, const u16* __restrict__ posT,
    u16* __restrict__ ab) {
  __shared__ __align__(16) u16 Ks[2][2][64 * 64];   // 32 KB (Ks[1][0] aliases Q pre-loop)
  __shared__ __align__(16) u16 Vt[2][2][64 * 64];   // 32 KB  [dh][key]
  __shared__ __align__(16) u16 Pt[4][16 * 64];      // 8 KB wave-private (XOR-swizzled)

  const int t = threadIdx.x;
  const int lane = t & 63, w = t >> 6;
  const int qd = lane >> 4, lr = lane & 15;

  // XCD-grouping remap (bijective on 512 blocks) — R4-proven
  const int flat = blockIdx.x + 16 * blockIdx.y + 256 * blockIdx.z;
  const int xcd = flat & 7;
  const int slot = flat >> 3;          // 0..63 within XCD
  const int gsub = slot >> 4;          // 0..3
  int qt = slot & 15;
  if (gsub & 2) qt = 15 - qt;          // complementary pairing on each CU
  const int g = gsub * 8 + xcd;        // (b,h) group 0..31
  const int h = g & 15;
  const int b = g >> 4;
  const int i0 = qt * 64;

  const int swz = ((t & 7) ^ ((t >> 3) & 7)) * 8;  // staging source-chunk swizzle
  const int c0 = (qd ^ (lr & 7)) * 8;              // fragment-read chunk offsets
  const int c1 = c0 ^ 32;
  const int row8 = t >> 3;

  const int jmax = min(K_, i0 + 64 + M_);

  // tiled pos fragment base: group for 64-key sub tt, frag pc is g0 + 4*tt + pc.
  // One-phase-ahead prefetch reaches group <= 143 -> 144-group posT stride.
  const int g0 = 63 - (i0 >> 4) - w;
  const u16* pb0 = posT + (size_t)b * 147456 + qd * 128 + lr * 8;

  // ---- pre-loop staging: Q -> Ks[1][0]; phase0 K/V (both subs) -> buf0 ----
#pragma unroll
  for (int rd = 0; rd < 2; rd++)
    gll16(qb + (size_t)(b * S_ + i0 + rd * 32 + row8) * 1024 + h * 64 + swz,
          &Ks[1][0][0] + rd * 2048 + w * 512);
#pragma unroll
  for (int sb = 0; sb < 2; sb++)
#pragma unroll
    for (int rd = 0; rd < 2; rd++) {
      gll16(kb + (size_t)(b * K_ + sb * 64 + rd * 32 + row8) * 1024 + h * 64 + swz,
            &Ks[0][sb][0] + rd * 2048 + w * 512);
      gll16(vbT + (size_t)((b * H_ + h) * 64 + rd * 32 + row8) * K_ + sb * 64 + swz,
            &Vt[0][sb][0] + rd * 2048 + w * 512);
    }
  // preload pos fragments for phase0 subs (registers, coalesced)
  short8 pgA0[5], pgA1[5], pgB0[5], pgB1[5];
  {
    const u16* pp = pb0 + (size_t)g0 * 1024;
#pragma unroll
    for (int pc = 0; pc < 5; pc++) {
      pgA0[pc] = *(const short8*)(pp + pc * 1024);
      pgA1[pc] = *(const short8*)(pp + pc * 1024 + 512);
    }
    const u16* p2 = pb0 + (size_t)(g0 + 4) * 1024;
#pragma unroll
    for (int pc = 0; pc < 5; pc++) {
      pgB0[pc] = *(const short8*)(p2 + pc * 1024);
      pgB1[pc] = *(const short8*)(p2 + pc * 1024 + 512);
    }
  }
  __syncthreads();
  const short8 aQ0 = *(const short8*)&Ks[1][0][(w * 16 + lr) * 64 + c0];
  const short8 aQ1 = *(const short8*)&Ks[1][0][(w * 16 + lr) * 64 + c1];

  f32x4 accO[4];
#pragma unroll
  for (int d = 0; d < 4; d++) accO[d] = (f32x4){0.f, 0.f, 0.f, 0.f};
  float lsum[4];
#pragma unroll
  for (int r = 0; r < 4; r++) lsum[r] = 0.f;

  for (int j0 = 0, ph = 0; j0 < jmax; j0 += 128, ph++) {
    __syncthreads();
    const int cb = ph & 1;
    const int nb = cb ^ 1;
    const int j0n = j0 + 128;
    // ---- stage phase+1 (per-sub guard; valid subs are fully in-bounds) ----
#pragma unroll
    for (int sb = 0; sb < 2; sb++)
      if (j0n + sb * 64 < jmax) {
#pragma unroll
        for (int rd = 0; rd < 2; rd++) {
          gll16(kb + (size_t)(b * K_ + j0n + sb * 64 + rd * 32 + row8) * 1024 + h * 64 + swz,
                &Ks[nb][sb][0] + rd * 2048 + w * 512);
          gll16(vbT + (size_t)((b * H_ + h) * 64 + rd * 32 + row8) * K_ + j0n + sb * 64 + swz,
                &Vt[nb][sb][0] + rd * 2048 + w * 512);
        }
      }

    // ================= SUB 0 (keys j0 .. j0+63) =================
    {
      __builtin_amdgcn_s_setprio(1);
      f32x4 zp[5];
#pragma unroll
      for (int pc = 0; pc < 5; pc++) {
        f32x4 z = {0.f, 0.f, 0.f, 0.f};
        z = mfma16(aQ0, pgA0[pc], z);
        zp[pc] = mfma16(aQ1, pgA1[pc], z);
      }
      f32x4 sqk[4];
#pragma unroll
      for (int kc = 0; kc < 4; kc++) {
        const short8 bK0 = *(const short8*)&Ks[cb][0][(kc * 16 + lr) * 64 + c0];
        const short8 bK1 = *(const short8*)&Ks[cb][0][(kc * 16 + lr) * 64 + c1];
        f32x4 z = {0.f, 0.f, 0.f, 0.f};
        z = mfma16(aQ0, bK0, z);
        sqk[kc] = mfma16(aQ1, bK1, z);
      }
      __builtin_amdgcn_s_setprio(0);
      // prefetch pgA for next phase's sub0 (tt = 2*ph+2)
      {
        const u16* pn = pb0 + (size_t)(g0 + 4 * (2 * ph + 2)) * 1024;
#pragma unroll
        for (int pc = 0; pc < 5; pc++) {
          pgA0[pc] = *(const short8*)(pn + pc * 1024);
          pgA1[pc] = *(const short8*)(pn + pc * 1024 + 512);
        }
      }
      // shuffle-based skew gather + max-free softmax
      const bool tail = (j0 + 63 > i0 + w * 16 + M_);
      float p[4][4];
#pragma unroll
      for (int r = 0; r < 4; r++) {
        const int iL = qd * 4 + r;
        const int d = 15 + lr - iL;
        const int srcl = qd * 16 + (d & 15);
        const bool hi = (d >> 4) & 1;
        float g0s = __shfl(zp[0][r], srcl, 64);
        float g1s = __shfl(zp[1][r], srcl, 64);
        float g2s = __shfl(zp[2][r], srcl, 64);
        float g3s = __shfl(zp[3][r], srcl, 64);
        float g4s = __shfl(zp[4][r], srcl, 64);
        float s0 = sqk[0][r] + (hi ? g1s : g0s);
        float s1 = sqk[1][r] + (hi ? g2s : g1s);
        float s2 = sqk[2][r] + (hi ? g3s : g2s);
        float s3 = sqk[3][r] + (hi ? g4s : g3s);
        if (tail) {
          const int key = j0 + lr, lim = i0 + w * 16 + iL + M_;
          if (key      > lim) s0 = NEG_BIG;
          if (key + 16 > lim) s1 = NEG_BIG;
          if (key + 32 > lim) s2 = NEG_BIG;
          if (key + 48 > lim) s3 = NEG_BIG;
        }
        p[0][r] = __expf(s0);
        p[1][r] = __expf(s1);
        p[2][r] = __expf(s2);
        p[3][r] = __expf(s3);
        lsum[r] += p[0][r] + p[1][r] + p[2][r] + p[3][r];
      }
      // P -> wave-private LDS (XOR chunk swizzle) -> A-fragments
#pragma unroll
      for (int r = 0; r < 4; r++) {
        const int row = qd * 4 + r;
        const int cbase = row * 64;
        const int rx = row & 7;
        const int lo = lr & 7, hi8 = lr >> 3;
#pragma unroll
        for (int kc = 0; kc < 4; kc++)
          Pt[w][cbase + ((((kc << 1) | hi8) ^ rx) << 3) + lo] = f2bf(p[kc][r]);
      }
      __asm__ volatile("s_waitcnt lgkmcnt(0)" ::: "memory");
      const short8 aP0 = *(const short8*)&Pt[w][lr * 64 + ((qd ^ (lr & 7)) << 3)];
      const short8 aP1 = *(const short8*)&Pt[w][lr * 64 + (((qd + 4) ^ (lr & 7)) << 3)];
      // P @ V
      __builtin_amdgcn_s_setprio(1);
#pragma unroll
      for (int d2 = 0; d2 < 4; d2++) {
        const short8 bV0 = *(const short8*)&Vt[cb][0][(d2 * 16 + lr) * 64 + c0];
        const short8 bV1 = *(const short8*)&Vt[cb][0][(d2 * 16 + lr) * 64 + c1];
        accO[d2] = mfma16(aP0, bV0, accO[d2]);
        accO[d2] = mfma16(aP1, bV1, accO[d2]);
      }
      __builtin_amdgcn_s_setprio(0);
    }

    // ================= SUB 1 (keys j0+64 .. j0+127) =================
    if (j0 + 64 < jmax) {
      const int j1 = j0 + 64;
      __builtin_amdgcn_s_setprio(1);
      f32x4 zp[5];
#pragma unroll
      for (int pc = 0; pc < 5; pc++) {
        f32x4 z = {0.f, 0.f, 0.f, 0.f};
        z = mfma16(aQ0, pgB0[pc], z);
        zp[pc] = mfma16(aQ1, pgB1[pc], z);
      }
      f32x4 sqk[4];
#pragma unroll
      for (int kc = 0; kc < 4; kc++) {
        const short8 bK0 = *(const short8*)&Ks[cb][1][(kc * 16 + lr) * 64 + c0];
        const short8 bK1 = *(const short8*)&Ks[cb][1][(kc * 16 + lr) * 64 + c1];
        f32x4 z = {0.f, 0.f, 0.f, 0.f};
        z = mfma16(aQ0, bK0, z);
        sqk[kc] = mfma16(aQ1, bK1, z);
      }
      __builtin_amdgcn_s_setprio(0);
      // prefetch pgB for next phase's sub1 (tt = 2*ph+3)
      {
        const u16* pn = pb0 + (size_t)(g0 + 4 * (2 * ph + 3)) * 1024;
#pragma unroll
        for (int pc = 0; pc < 5; pc++) {
          pgB0[pc] = *(const short8*)(pn + pc * 1024);
          pgB1[pc] = *(const short8*)(pn + pc * 1024 + 512);
        }
      }
      const bool tail = (j1 + 63 > i0 + w * 16 + M_);
      float p[4][4];
#pragma unroll
      for (int r = 0; r < 4; r++) {
        const int iL = qd * 4 + r;
        const int d = 15 + lr - iL;
        const int srcl = qd * 16 + (d & 15);
        const bool hi = (d >> 4) & 1;
        float g0s = __shfl(zp[0][r], srcl, 64);
        float g1s = __shfl(zp[1][r], srcl, 64);
        float g2s = __shfl(zp[2][r], srcl, 64);
        float g3s = __shfl(zp[3][r], srcl, 64);
        float g4s = __shfl(zp[4][r], srcl, 64);
        float s0 = sqk[0][r] + (hi ? g1s : g0s);
        float s1 = sqk[1][r] + (hi ? g2s : g1s);
        float s2 = sqk[2][r] + (hi ? g3s : g2s);
        float s3 = sqk[3][r] + (hi ? g4s : g3s);
        if (tail) {
          const int key = j1 + lr, lim = i0 + w * 16 + iL + M_;
          if (key      > lim) s0 = NEG_BIG;
          if (key + 16 > lim) s1 = NEG_BIG;
          if (key + 32 > lim) s2 = NEG_BIG;
          if (key + 48 > lim) s3 = NEG_BIG;
        }
        p[0][r] = __expf(s0);
        p[1][r] = __expf(s1);
        p[2][r] = __expf(s2);
        p[3][r] = __expf(s3);
        lsum[r] += p[0][r] + p[1][r] + p[2][r] + p[3][r];
      }
#pragma unroll
      for (int r = 0; r < 4; r++) {
        const int row = qd * 4 + r;
        const int cbase = row * 64;
        const int rx = row & 7;
        const int lo = lr & 7, hi8 = lr >> 3;
#pragma unroll
        for (int kc = 0; kc < 4; kc++)
          Pt[w][cbase + ((((kc << 1) | hi8) ^ rx) << 3) + lo] = f2bf(p[kc][r]);
      }
      __asm__ volatile("s_waitcnt lgkmcnt(0)" ::: "memory");
      const short8 aP0 = *(const short8*)&Pt[w][lr * 64 + ((qd ^ (lr & 7)) << 3)];
      const short8 aP1 = *(const short8*)&Pt[w][lr * 64 + (((qd + 4) ^ (lr & 7)) << 3)];
      __builtin_amdgcn_s_setprio(1);
#pragma unroll
      for (int d2 = 0; d2 < 4; d2++) {
        const short8 bV0 = *(const short8*)&Vt[cb][1][(d2 * 16 + lr) * 64 + c0];
        const short8 bV1 = *(const short8*)&Vt[cb][1][(d2 * 16 + lr) * 64 + c1];
        accO[d2] = mfma16(aP0, bV0, accO[d2]);
        accO[d2] = mfma16(aP1, bV1, accO[d2]);
      }
      __builtin_amdgcn_s_setprio(0);
    }
  }

  // ---- epilogue: one 16-lane reduction of lsum, then normalize ----
  float inv[4];
#pragma unroll
  for (int r = 0; r < 4; r++) {
#pragma unroll
    for (int msk = 1; msk < 16; msk <<= 1) lsum[r] += __shfl_xor(lsum[r], msk, 64);
    inv[r] = 1.0f / lsum[r];
  }
#pragma unroll
  for (int d2 = 0; d2 < 4; d2++)
#pragma unroll
    for (int r = 0; r < 4; r++) {
      const int iG = i0 + w * 16 + qd * 4 + r;
      ab[(size_t)(b * S_ + iG) * 1024 + h * 64 + d2 * 16 + lr] = f2bf(accO[d2][r] * inv[r]);
    }
}

// ---------------- launch ----------------
extern "C" void kernel_launch(void* const* d_in, const int* in_sizes, int n_in,
                              void* d_out, int out_size, void* d_ws, size_t ws_size,
                              hipStream_t stream) {
  const float* hidden = (const float*)d_in[0];
  const float* pos    = (const float*)d_in[1];
  const float* memory = (const float*)d_in[2];
  // d_in[3] = mask (bool) — causality applied analytically, unused
  const float* Wq = (const float*)d_in[4];
  const float* Wk = (const float*)d_in[5];
  const float* Wv = (const float*)d_in[6];
  const float* Wo = (const float*)d_in[7];
  const float* gamma = (const float*)d_in[8];
  const float* beta  = (const float*)d_in[9];

  char* ws = (char*)d_ws;
  u16* cln  = (u16*)(ws);               // 8 MB
  u16* qb   = (u16*)(ws + 8388608);     // 4 MB (pre-scaled 1/32)
  u16* kb   = (u16*)(ws + 12582912);    // 8 MB
  u16* vbT  = (u16*)(ws + 20971520);    // 8 MB
  u16* ab   = (u16*)(ws + 29360128);    // 4 MB
  u16* WqT  = (u16*)(ws + 33554432);    // 4 x 2 MB contiguous (WqT|WkT|WvT|WoT)
  u16* WkT  = WqT + 1048576;
  u16* WvT  = WkT + 1048576;
  u16* WoT  = WvT + 1048576;
  u16* posT = (u16*)(ws + 41943040);    // 0.56 MB tiled pos (144-group stride)

  prep_kernel<<<dim3(5256), 256, 0, stream>>>(
      hidden, memory, gamma, beta, cln,
      Wq, Wk, Wv, Wo, WqT, WkT, WvT, WoT, pos, posT);
  gemm_qkv_kernel<<<dim3(24, 32), 256, 0, stream>>>(cln, WqT, qb, kb, vbT);
  attn_kernel<<<dim3(S_ / 64, H_, B_), 256, 0, stream>>>(qb, kb, vbT, posT, ab);
  out_gemm_kernel<<<dim3(16, 16), 256, 0, stream>>>(ab, WoT, cln, (float*)d_out);
}

// Round 11
// 193.600 us; speedup vs baseline: 1.3557x; 1.0446x over previous
//
#include <hip/hip_runtime.h>
#include <hip/hip_bf16.h>

// Problem constants (B,S,M,D,H,DH = 2,1024,1024,1024,16,64)
#define B_ 2
#define S_ 1024
#define M_ 1024
#define D_ 1024
#define H_ 16
#define DH_ 64
#define K_ 2048
#define R_ 4095

// finite stand-in for -inf (avoids inf arithmetic under fast-math)
#define NEG_BIG (-1e30f)

typedef unsigned short u16;
typedef short short8 __attribute__((ext_vector_type(8)));
typedef float f32x4 __attribute__((ext_vector_type(4)));

__device__ __forceinline__ u16 f2bf(float f) {
  __hip_bfloat16 h = __float2bfloat16(f);
  return *reinterpret_cast<u16*>(&h);
}
__device__ __forceinline__ float bf2f(u16 u) {
  __hip_bfloat16 h;
  *reinterpret_cast<u16*>(&h) = u;
  return __bfloat162float(h);
}

// async global->LDS, 16B per lane; LDS dest = wave-uniform base + lane*16
__device__ __forceinline__ void gll16(const void* g, const void* l) {
  __builtin_amdgcn_global_load_lds(
      (const __attribute__((address_space(1))) unsigned int*)g,
      (__attribute__((address_space(3))) unsigned int*)l, 16, 0, 0);
}

__device__ __forceinline__ f32x4 mfma16(short8 a, short8 b, f32x4 c) {
  return __builtin_amdgcn_mfma_f32_16x16x32_bf16(a, b, c, 0, 0, 0);
}

// ---------------- fused prep: LN(concat) + 4x weight transpose + pos tiled cvt ----------
// posT layout: [b][g<144][oct<8][r<16][j<8] bf16 (136 groups written, 8 pad groups
// readable-garbage for the one-phase-ahead prefetch), so an attn pos-fragment load
// (rows g*16+lr, cols oct*8..+8) is ONE contiguous 1KB wave transaction.
__global__ __launch_bounds__(256) void prep_kernel(
    const float* __restrict__ hidden, const float* __restrict__ memory,
    const float* __restrict__ gamma, const float* __restrict__ beta,
    u16* __restrict__ cln,
    const float* __restrict__ W0, const float* __restrict__ W1,
    const float* __restrict__ W2, const float* __restrict__ W3,
    u16* __restrict__ O0, u16* __restrict__ O1,
    u16* __restrict__ O2, u16* __restrict__ O3,
    const float* __restrict__ pos, u16* __restrict__ posT) {
  __shared__ u16 tile[64][66];
  __shared__ float red[8];
  const int bx = blockIdx.x;
  const int t = threadIdx.x;

  if (bx < 4096) {  // LayerNorm row
    const int b = bx >> 11;
    const int idx = bx & (K_ - 1);
    const float* src = (idx < M_)
        ? memory + (size_t)(b * M_ + idx) * D_
        : hidden + (size_t)(b * S_ + (idx - M_)) * D_;
    const int lane = t & 63, w = t >> 6;
    float4 rv = ((const float4*)src)[t];
    float s = rv.x + rv.y + rv.z + rv.w;
    float ss = rv.x * rv.x + rv.y * rv.y + rv.z * rv.z + rv.w * rv.w;
#pragma unroll
    for (int m = 1; m < 64; m <<= 1) {
      s += __shfl_xor(s, m, 64);
      ss += __shfl_xor(ss, m, 64);
    }
    if (lane == 0) { red[w] = s; red[4 + w] = ss; }
    __syncthreads();
    s = red[0] + red[1] + red[2] + red[3];
    ss = red[4] + red[5] + red[6] + red[7];
    const float mu = s * (1.0f / D_);
    const float var = ss * (1.0f / D_) - mu * mu;
    const float rstd = rsqrtf(var + 1e-5f);
    float4 gv = ((const float4*)gamma)[t];
    float4 bv = ((const float4*)beta)[t];
    ushort4 ov;
    ov.x = f2bf((rv.x - mu) * rstd * gv.x + bv.x);
    ov.y = f2bf((rv.y - mu) * rstd * gv.y + bv.y);
    ov.z = f2bf((rv.z - mu) * rstd * gv.z + bv.z);
    ov.w = f2bf((rv.w - mu) * rstd * gv.w + bv.w);
    ((ushort4*)(cln + (size_t)bx * D_))[t] = ov;
    return;
  }
  if (bx < 5120) {  // weight transpose slab
    const int z = (bx - 4096) >> 8;
    const int rem = (bx - 4096) & 255;
    const float* in; u16* out;
    switch (z) {
      case 0:  in = W0; out = O0; break;
      case 1:  in = W1; out = O1; break;
      case 2:  in = W2; out = O2; break;
      default: in = W3; out = O3; break;
    }
    const int tx = t & 63, ty = t >> 6;
    const int k0 = (rem & 15) * 64, n0 = (rem >> 4) * 64;
#pragma unroll
    for (int i = ty; i < 64; i += 4)
      tile[i][tx] = f2bf(in[(size_t)(k0 + i) * D_ + n0 + tx]);
    __syncthreads();
#pragma unroll
    for (int i = ty; i < 64; i += 4)
      out[(size_t)(n0 + i) * D_ + k0 + tx] = tile[tx][i];
    return;
  }
  // pos f32 -> bf16, tiled: u enumerates (b, g, r, oct); 136 groups of 16 rows per batch
  {
    const int u = (bx - 5120) * 256 + t;    // [0, 34816)
    const int oct = u & 7;
    const int r = (u >> 3) & 15;
    const int g = (u >> 7) % 136;
    const int b = u / 17408;                // 136*128
    const int row = g * 16 + r;             // <= 2175 < R_ (always in-bounds)
    const float* s = pos + ((size_t)b * R_ + row) * 64 + oct * 8;
    float4 v0 = ((const float4*)s)[0];
    float4 v1 = ((const float4*)s)[1];
    ushort4 oA, oB;
    oA.x = f2bf(v0.x); oA.y = f2bf(v0.y); oA.z = f2bf(v0.z); oA.w = f2bf(v0.w);
    oB.x = f2bf(v1.x); oB.y = f2bf(v1.y); oB.z = f2bf(v1.z); oB.w = f2bf(v1.w);
    u16* d = posT + (size_t)(b * 144 + g) * 1024 + oct * 128 + r * 8;  // 144-group stride
    ((ushort4*)d)[0] = oA;
    ((ushort4*)d)[1] = oB;
  }
}

// row r of the "hidden slice" view -> row of c_ln
__device__ __forceinline__ int maprow_hidden(int r) {
  return r + ((r >> 10) << 10) + M_;
}

// ---------------- QKV GEMM: BK=64, XOR-swizzled staging, 3 blocks/CU ----------------
// LDS-staged coalesced epilogue: old epilogue did 80 scattered stores/thread
// (V: 64 lanes x 8B to 64 DIFFERENT K-stride rows = 64 L2 lines/instr; K/Q: scalar
// u16 in 32B segments). Now: stage the 128x128 tile in LDS [128][132] (pad-132 ->
// conflict-free staging), then 8 x 16B fully-coalesced short8 stores per thread.
__global__ __launch_bounds__(256, 3) void gemm_qkv_kernel(
    const u16* __restrict__ A, const u16* __restrict__ Bt,
    u16* __restrict__ qb, u16* __restrict__ kb, u16* __restrict__ vbT) {
  __shared__ __align__(16) u16 shm[128 * 132];   // 33 KB: As|Bs during loop, C-tile after
  u16* As = shm;                 // 128*64
  u16* Bs = shm + 8192;          // 128*64
  const int t = threadIdx.x;
  const int lane = t & 63, w = t >> 6;
  const int wm = w >> 1, wn = w & 1;
  const int qd = lane >> 4, lr = lane & 15;
  const int m0 = blockIdx.y * 128, n0 = blockIdx.x * 128;
  if (n0 < 1024 && !(m0 & 1024)) return;   // dead Q tiles (memory rows)

  const int swz = ((t & 7) ^ ((t >> 3) & 7)) * 8;  // source-chunk swizzle
  const int c0 = (qd ^ (lr & 7)) * 8;
  const int c1 = c0 ^ 32;
  const int row8 = (t >> 3) & 7;

  f32x4 acc[4][4];
#pragma unroll
  for (int mt = 0; mt < 4; mt++)
#pragma unroll
    for (int nt = 0; nt < 4; nt++) acc[mt][nt] = (f32x4){0.f, 0.f, 0.f, 0.f};

  for (int kt = 0; kt < 1024; kt += 64) {
#pragma unroll
    for (int p = 0; p < 4; p++) {
      const int ra = w * 32 + p * 8 + row8;
      gll16(A + (size_t)(m0 + ra) * 1024 + kt + swz, As + (w * 32 + p * 8) * 64);
      gll16(Bt + (size_t)(n0 + ra) * 1024 + kt + swz, Bs + (w * 32 + p * 8) * 64);
    }
    __syncthreads();
    short8 a0[4], a1[4], b0[4], b1[4];
#pragma unroll
    for (int mt = 0; mt < 4; mt++) {
      a0[mt] = *(const short8*)&As[(wm * 64 + mt * 16 + lr) * 64 + c0];
      a1[mt] = *(const short8*)&As[(wm * 64 + mt * 16 + lr) * 64 + c1];
    }
#pragma unroll
    for (int nt = 0; nt < 4; nt++) {
      b0[nt] = *(const short8*)&Bs[(wn * 64 + nt * 16 + lr) * 64 + c0];
      b1[nt] = *(const short8*)&Bs[(wn * 64 + nt * 16 + lr) * 64 + c1];
    }
#pragma unroll
    for (int mt = 0; mt < 4; mt++)
#pragma unroll
      for (int nt = 0; nt < 4; nt++) {
        acc[mt][nt] = mfma16(a0[mt], b0[nt], acc[mt][nt]);
        acc[mt][nt] = mfma16(a1[mt], b1[nt], acc[mt][nt]);
      }
    __syncthreads();
  }

  // ---- epilogue: stage C-tile (or C^T for V) into LDS, then coalesced stores ----
  const bool isV = (n0 >= 2048);
  if (!isV) {                    // Q (scaled) or K: row-major [row][col], pad 132
    const float sc = (n0 < 1024) ? 0.03125f : 1.0f;
#pragma unroll
    for (int mt = 0; mt < 4; mt++)
#pragma unroll
      for (int nt = 0; nt < 4; nt++) {
        const int row0 = wm * 64 + mt * 16 + qd * 4;
        const int col = wn * 64 + nt * 16 + lr;
#pragma unroll
        for (int r = 0; r < 4; r++)
          shm[(row0 + r) * 132 + col] = f2bf(acc[mt][nt][r] * sc);
      }
  } else {                       // V: transposed [nn][kk], ushort4 along kk
#pragma unroll
    for (int mt = 0; mt < 4; mt++)
#pragma unroll
      for (int nt = 0; nt < 4; nt++) {
        const int kk0 = wm * 64 + mt * 16 + qd * 4;
        const int nn = wn * 64 + nt * 16 + lr;
        ushort4 pk;
        pk.x = f2bf(acc[mt][nt][0]);
        pk.y = f2bf(acc[mt][nt][1]);
        pk.z = f2bf(acc[mt][nt][2]);
        pk.w = f2bf(acc[mt][nt][3]);
        *(ushort4*)&shm[nn * 132 + kk0] = pk;
      }
  }
  __syncthreads();
  // 2048 16B-chunks (128 rows x 16), 8 per thread; consecutive t -> contiguous 256B runs
  const int bq = m0 >> 11;
#pragma unroll
  for (int i = 0; i < 8; i++) {
    const int flat = i * 256 + t;
    const int row = flat >> 4;
    const int ch = flat & 15;
    const ushort4 v0 = *(const ushort4*)&shm[row * 132 + ch * 8];
    const ushort4 v1 = *(const ushort4*)&shm[row * 132 + ch * 8 + 4];
    u16* dst;
    if (n0 < 1024) {
      const int qrow = (bq << 10) | ((m0 + row) & 1023);
      dst = qb + (size_t)qrow * 1024 + n0 + ch * 8;
    } else if (!isV) {
      const int key = (m0 + row) & (K_ - 1);
      dst = kb + (size_t)(bq * K_ + key) * 1024 + (n0 - 1024) + ch * 8;
    } else {
      const int dhg = (n0 - 2048) + row;           // global nn within batch
      const int bh = (bq << 4) | (dhg >> 6);
      const int dh = dhg & 63;
      dst = vbT + (size_t)(bh * 64 + dh) * K_ + (m0 & (K_ - 1)) + ch * 8;
    }
    short8 vv;
    *(ushort4*)&vv = v0;
    *(((ushort4*)&vv) + 1) = v1;
    *(short8*)dst = vv;          // one 16B coalesced store
  }
}

// ---------------- out GEMM: 128x64 tiles, BK=64, XOR-swizzled (qkv's proven pattern) ----
__global__ __launch_bounds__(256, 2) void out_gemm_kernel(
    const u16* __restrict__ A, const u16* __restrict__ Bt,
    const u16* __restrict__ resid, float* __restrict__ Cf) {
  __shared__ __align__(16) u16 As[128 * 64];   // 16 KB
  __shared__ __align__(16) u16 Bs[64 * 64];    // 8 KB
  const int t = threadIdx.x;
  const int lane = t & 63, w = t >> 6;
  const int wm = w >> 1, wn = w & 1;
  const int qd = lane >> 4, lr = lane & 15;
  const int m0 = blockIdx.y * 128, n0 = blockIdx.x * 64;

  const int swz = ((t & 7) ^ ((t >> 3) & 7)) * 8;  // source-chunk swizzle
  const int c0 = (qd ^ (lr & 7)) * 8;              // fragment-read chunk offsets
  const int c1 = c0 ^ 32;
  const int row8 = (t >> 3) & 7;

  f32x4 acc[4][2];
#pragma unroll
  for (int mt = 0; mt < 4; mt++)
#pragma unroll
    for (int nt = 0; nt < 2; nt++) acc[mt][nt] = (f32x4){0.f, 0.f, 0.f, 0.f};

  for (int kt = 0; kt < 1024; kt += 64) {
#pragma unroll
    for (int p = 0; p < 4; p++) {   // As rows 0..127
      const int ra = w * 32 + p * 8 + row8;
      gll16(A + (size_t)(m0 + ra) * 1024 + kt + swz, As + (w * 32 + p * 8) * 64);
    }
#pragma unroll
    for (int p = 0; p < 2; p++) {   // Bs rows 0..63
      const int rb = w * 16 + p * 8 + row8;
      gll16(Bt + (size_t)(n0 + rb) * 1024 + kt + swz, Bs + (w * 16 + p * 8) * 64);
    }
    __syncthreads();
    short8 a0[4], a1[4], b0[2], b1[2];
#pragma unroll
    for (int mt = 0; mt < 4; mt++) {
      a0[mt] = *(const short8*)&As[(wm * 64 + mt * 16 + lr) * 64 + c0];
      a1[mt] = *(const short8*)&As[(wm * 64 + mt * 16 + lr) * 64 + c1];
    }
#pragma unroll
    for (int nt = 0; nt < 2; nt++) {
      b0[nt] = *(const short8*)&Bs[(wn * 32 + nt * 16 + lr) * 64 + c0];
      b1[nt] = *(const short8*)&Bs[(wn * 32 + nt * 16 + lr) * 64 + c1];
    }
#pragma unroll
    for (int mt = 0; mt < 4; mt++)
#pragma unroll
      for (int nt = 0; nt < 2; nt++) {
        acc[mt][nt] = mfma16(a0[mt], b0[nt], acc[mt][nt]);
        acc[mt][nt] = mfma16(a1[mt], b1[nt], acc[mt][nt]);
      }
    __syncthreads();
  }

#pragma unroll
  for (int mt = 0; mt < 4; mt++)
#pragma unroll
    for (int nt = 0; nt < 2; nt++)
#pragma unroll
      for (int r = 0; r < 4; r++) {
        const int row = m0 + wm * 64 + mt * 16 + qd * 4 + r;
        const int col = n0 + wn * 32 + nt * 16 + lr;
        float v = acc[mt][nt][r] + bf2f(resid[(size_t)maprow_hidden(row) * 1024 + col]);
        Cf[(size_t)row * 1024 + col] = v;
      }
}

// ---------------- attention: KVBLK=128 (two 64-key sub-tiles per barrier phase) --------
// R4 memory behavior kept verbatim (XCD-grouped remap, FETCH 12 MB proven; tiled posT
// in registers). One barrier per 128 keys halves sync/drain overhead and doubles the
// scheduler window. Ks/Vt double-buffered at phase granularity; Pt single-buffered
// (wave-private, in-order DS). LDS 72 KB, 2 blocks/CU. grid (16, H, B).
__global__ __launch_bounds__(256, 2) void attn_kernel(
    const u16* __restrict__ qb, const u16* __restrict__ kb,
    const u16* __restrict__ vbT, const u16* __restrict__ posT,
    u16* __restrict__ ab) {
  __shared__ __align__(16) u16 Ks[2][2][64 * 64];   // 32 KB (Ks[1][0] aliases Q pre-loop)
  __shared__ __align__(16) u16 Vt[2][2][64 * 64];   // 32 KB  [dh][key]
  __shared__ __align__(16) u16 Pt[4][16 * 64];      // 8 KB wave-private (XOR-swizzled)

  const int t = threadIdx.x;
  const int lane = t & 63, w = t >> 6;
  const int qd = lane >> 4, lr = lane & 15;

  // XCD-grouping remap (bijective on 512 blocks) — R4-proven
  const int flat = blockIdx.x + 16 * blockIdx.y + 256 * blockIdx.z;
  const int xcd = flat & 7;
  const int slot = flat >> 3;          // 0..63 within XCD
  const int gsub = slot >> 4;          // 0..3
  int qt = slot & 15;
  if (gsub & 2) qt = 15 - qt;          // complementary pairing on each CU
  const int g = gsub * 8 + xcd;        // (b,h) group 0..31
  const int h = g & 15;
  const int b = g >> 4;
  const int i0 = qt * 64;

  const int swz = ((t & 7) ^ ((t >> 3) & 7)) * 8;  // staging source-chunk swizzle
  const int c0 = (qd ^ (lr & 7)) * 8;              // fragment-read chunk offsets
  const int c1 = c0 ^ 32;
  const int row8 = t >> 3;

  const int jmax = min(K_, i0 + 64 + M_);

  // tiled pos fragment base: group for 64-key sub tt, frag pc is g0 + 4*tt + pc.
  // One-phase-ahead prefetch reaches group <= 143 -> 144-group posT stride.
  const int g0 = 63 - (i0 >> 4) - w;
  const u16* pb0 = posT + (size_t)b * 147456 + qd * 128 + lr * 8;

  // ---- pre-loop staging: Q -> Ks[1][0]; phase0 K/V (both subs) -> buf0 ----
#pragma unroll
  for (int rd = 0; rd < 2; rd++)
    gll16(qb + (size_t)(b * S_ + i0 + rd * 32 + row8) * 1024 + h * 64 + swz,
          &Ks[1][0][0] + rd * 2048 + w * 512);
#pragma unroll
  for (int sb = 0; sb < 2; sb++)
#pragma unroll
    for (int rd = 0; rd < 2; rd++) {
      gll16(kb + (size_t)(b * K_ + sb * 64 + rd * 32 + row8) * 1024 + h * 64 + swz,
            &Ks[0][sb][0] + rd * 2048 + w * 512);
      gll16(vbT + (size_t)((b * H_ + h) * 64 + rd * 32 + row8) * K_ + sb * 64 + swz,
            &Vt[0][sb][0] + rd * 2048 + w * 512);
    }
  // preload pos fragments for phase0 subs (registers, coalesced)
  short8 pgA0[5], pgA1[5], pgB0[5], pgB1[5];
  {
    const u16* pp = pb0 + (size_t)g0 * 1024;
#pragma unroll
    for (int pc = 0; pc < 5; pc++) {
      pgA0[pc] = *(const short8*)(pp + pc * 1024);
      pgA1[pc] = *(const short8*)(pp + pc * 1024 + 512);
    }
    const u16* p2 = pb0 + (size_t)(g0 + 4) * 1024;
#pragma unroll
    for (int pc = 0; pc < 5; pc++) {
      pgB0[pc] = *(const short8*)(p2 + pc * 1024);
      pgB1[pc] = *(const short8*)(p2 + pc * 1024 + 512);
    }
  }
  __syncthreads();
  const short8 aQ0 = *(const short8*)&Ks[1][0][(w * 16 + lr) * 64 + c0];
  const short8 aQ1 = *(const short8*)&Ks[1][0][(w * 16 + lr) * 64 + c1];

  f32x4 accO[4];
#pragma unroll
  for (int d = 0; d < 4; d++) accO[d] = (f32x4){0.f, 0.f, 0.f, 0.f};
  float lsum[4];
#pragma unroll
  for (int r = 0; r < 4; r++) lsum[r] = 0.f;

  for (int j0 = 0, ph = 0; j0 < jmax; j0 += 128, ph++) {
    __syncthreads();
    const int cb = ph & 1;
    const int nb = cb ^ 1;
    const int j0n = j0 + 128;
    // ---- stage phase+1 (per-sub guard; valid subs are fully in-bounds) ----
#pragma unroll
    for (int sb = 0; sb < 2; sb++)
      if (j0n + sb * 64 < jmax) {
#pragma unroll
        for (int rd = 0; rd < 2; rd++) {
          gll16(kb + (size_t)(b * K_ + j0n + sb * 64 + rd * 32 + row8) * 1024 + h * 64 + swz,
                &Ks[nb][sb][0] + rd * 2048 + w * 512);
          gll16(vbT + (size_t)((b * H_ + h) * 64 + rd * 32 + row8) * K_ + j0n + sb * 64 + swz,
                &Vt[nb][sb][0] + rd * 2048 + w * 512);
        }
      }

    // ================= SUB 0 (keys j0 .. j0+63) =================
    {
      __builtin_amdgcn_s_setprio(1);
      f32x4 zp[5];
#pragma unroll
      for (int pc = 0; pc < 5; pc++) {
        f32x4 z = {0.f, 0.f, 0.f, 0.f};
        z = mfma16(aQ0, pgA0[pc], z);
        zp[pc] = mfma16(aQ1, pgA1[pc], z);
      }
      f32x4 sqk[4];
#pragma unroll
      for (int kc = 0; kc < 4; kc++) {
        const short8 bK0 = *(const short8*)&Ks[cb][0][(kc * 16 + lr) * 64 + c0];
        const short8 bK1 = *(const short8*)&Ks[cb][0][(kc * 16 + lr) * 64 + c1];
        f32x4 z = {0.f, 0.f, 0.f, 0.f};
        z = mfma16(aQ0, bK0, z);
        sqk[kc] = mfma16(aQ1, bK1, z);
      }
      __builtin_amdgcn_s_setprio(0);
      // prefetch pgA for next phase's sub0 (tt = 2*ph+2)
      {
        const u16* pn = pb0 + (size_t)(g0 + 4 * (2 * ph + 2)) * 1024;
#pragma unroll
        for (int pc = 0; pc < 5; pc++) {
          pgA0[pc] = *(const short8*)(pn + pc * 1024);
          pgA1[pc] = *(const short8*)(pn + pc * 1024 + 512);
        }
      }
      // shuffle-based skew gather + max-free softmax
      const bool tail = (j0 + 63 > i0 + w * 16 + M_);
      float p[4][4];
#pragma unroll
      for (int r = 0; r < 4; r++) {
        const int iL = qd * 4 + r;
        const int d = 15 + lr - iL;
        const int srcl = qd * 16 + (d & 15);
        const bool hi = (d >> 4) & 1;
        float g0s = __shfl(zp[0][r], srcl, 64);
        float g1s = __shfl(zp[1][r], srcl, 64);
        float g2s = __shfl(zp[2][r], srcl, 64);
        float g3s = __shfl(zp[3][r], srcl, 64);
        float g4s = __shfl(zp[4][r], srcl, 64);
        float s0 = sqk[0][r] + (hi ? g1s : g0s);
        float s1 = sqk[1][r] + (hi ? g2s : g1s);
        float s2 = sqk[2][r] + (hi ? g3s : g2s);
        float s3 = sqk[3][r] + (hi ? g4s : g3s);
        if (tail) {
          const int key = j0 + lr, lim = i0 + w * 16 + iL + M_;
          if (key      > lim) s0 = NEG_BIG;
          if (key + 16 > lim) s1 = NEG_BIG;
          if (key + 32 > lim) s2 = NEG_BIG;
          if (key + 48 > lim) s3 = NEG_BIG;
        }
        p[0][r] = __expf(s0);
        p[1][r] = __expf(s1);
        p[2][r] = __expf(s2);
        p[3][r] = __expf(s3);
        lsum[r] += p[0][r] + p[1][r] + p[2][r] + p[3][r];
      }
      // P -> wave-private LDS (XOR chunk swizzle) -> A-fragments
#pragma unroll
      for (int r = 0; r < 4; r++) {
        const int row = qd * 4 + r;
        const int cbase = row * 64;
        const int rx = row & 7;
        const int lo = lr & 7, hi8 = lr >> 3;
#pragma unroll
        for (int kc = 0; kc < 4; kc++)
          Pt[w][cbase + ((((kc << 1) | hi8) ^ rx) << 3) + lo] = f2bf(p[kc][r]);
      }
      __asm__ volatile("s_waitcnt lgkmcnt(0)" ::: "memory");
      const short8 aP0 = *(const short8*)&Pt[w][lr * 64 + ((qd ^ (lr & 7)) << 3)];
      const short8 aP1 = *(const short8*)&Pt[w][lr * 64 + (((qd + 4) ^ (lr & 7)) << 3)];
      // P @ V
      __builtin_amdgcn_s_setprio(1);
#pragma unroll
      for (int d2 = 0; d2 < 4; d2++) {
        const short8 bV0 = *(const short8*)&Vt[cb][0][(d2 * 16 + lr) * 64 + c0];
        const short8 bV1 = *(const short8*)&Vt[cb][0][(d2 * 16 + lr) * 64 + c1];
        accO[d2] = mfma16(aP0, bV0, accO[d2]);
        accO[d2] = mfma16(aP1, bV1, accO[d2]);
      }
      __builtin_amdgcn_s_setprio(0);
    }

    // ================= SUB 1 (keys j0+64 .. j0+127) =================
    if (j0 + 64 < jmax) {
      const int j1 = j0 + 64;
      __builtin_amdgcn_s_setprio(1);
      f32x4 zp[5];
#pragma unroll
      for (int pc = 0; pc < 5; pc++) {
        f32x4 z = {0.f, 0.f, 0.f, 0.f};
        z = mfma16(aQ0, pgB0[pc], z);
        zp[pc] = mfma16(aQ1, pgB1[pc], z);
      }
      f32x4 sqk[4];
#pragma unroll
      for (int kc = 0; kc < 4; kc++) {
        const short8 bK0 = *(const short8*)&Ks[cb][1][(kc * 16 + lr) * 64 + c0];
        const short8 bK1 = *(const short8*)&Ks[cb][1][(kc * 16 + lr) * 64 + c1];
        f32x4 z = {0.f, 0.f, 0.f, 0.f};
        z = mfma16(aQ0, bK0, z);
        sqk[kc] = mfma16(aQ1, bK1, z);
      }
      __builtin_amdgcn_s_setprio(0);
      // prefetch pgB for next phase's sub1 (tt = 2*ph+3)
      {
        const u16* pn = pb0 + (size_t)(g0 + 4 * (2 * ph + 3)) * 1024;
#pragma unroll
        for (int pc = 0; pc < 5; pc++) {
          pgB0[pc] = *(const short8*)(pn + pc * 1024);
          pgB1[pc] = *(const short8*)(pn + pc * 1024 + 512);
        }
      }
      const bool tail = (j1 + 63 > i0 + w * 16 + M_);
      float p[4][4];
#pragma unroll
      for (int r = 0; r < 4; r++) {
        const int iL = qd * 4 + r;
        const int d = 15 + lr - iL;
        const int srcl = qd * 16 + (d & 15);
        const bool hi = (d >> 4) & 1;
        float g0s = __shfl(zp[0][r], srcl, 64);
        float g1s = __shfl(zp[1][r], srcl, 64);
        float g2s = __shfl(zp[2][r], srcl, 64);
        float g3s = __shfl(zp[3][r], srcl, 64);
        float g4s = __shfl(zp[4][r], srcl, 64);
        float s0 = sqk[0][r] + (hi ? g1s : g0s);
        float s1 = sqk[1][r] + (hi ? g2s : g1s);
        float s2 = sqk[2][r] + (hi ? g3s : g2s);
        float s3 = sqk[3][r] + (hi ? g4s : g3s);
        if (tail) {
          const int key = j1 + lr, lim = i0 + w * 16 + iL + M_;
          if (key      > lim) s0 = NEG_BIG;
          if (key + 16 > lim) s1 = NEG_BIG;
          if (key + 32 > lim) s2 = NEG_BIG;
          if (key + 48 > lim) s3 = NEG_BIG;
        }
        p[0][r] = __expf(s0);
        p[1][r] = __expf(s1);
        p[2][r] = __expf(s2);
        p[3][r] = __expf(s3);
        lsum[r] += p[0][r] + p[1][r] + p[2][r] + p[3][r];
      }
#pragma unroll
      for (int r = 0; r < 4; r++) {
        const int row = qd * 4 + r;
        const int cbase = row * 64;
        const int rx = row & 7;
        const int lo = lr & 7, hi8 = lr >> 3;
#pragma unroll
        for (int kc = 0; kc < 4; kc++)
          Pt[w][cbase + ((((kc << 1) | hi8) ^ rx) << 3) + lo] = f2bf(p[kc][r]);
      }
      __asm__ volatile("s_waitcnt lgkmcnt(0)" ::: "memory");
      const short8 aP0 = *(const short8*)&Pt[w][lr * 64 + ((qd ^ (lr & 7)) << 3)];
      const short8 aP1 = *(const short8*)&Pt[w][lr * 64 + (((qd + 4) ^ (lr & 7)) << 3)];
      __builtin_amdgcn_s_setprio(1);
#pragma unroll
      for (int d2 = 0; d2 < 4; d2++) {
        const short8 bV0 = *(const short8*)&Vt[cb][1][(d2 * 16 + lr) * 64 + c0];
        const short8 bV1 = *(const short8*)&Vt[cb][1][(d2 * 16 + lr) * 64 + c1];
        accO[d2] = mfma16(aP0, bV0, accO[d2]);
        accO[d2] = mfma16(aP1, bV1, accO[d2]);
      }
      __builtin_amdgcn_s_setprio(0);
    }
  }

  // ---- epilogue: one 16-lane reduction of lsum, then normalize ----
  float inv[4];
#pragma unroll
  for (int r = 0; r < 4; r++) {
#pragma unroll
    for (int msk = 1; msk < 16; msk <<= 1) lsum[r] += __shfl_xor(lsum[r], msk, 64);
    inv[r] = 1.0f / lsum[r];
  }
#pragma unroll
  for (int d2 = 0; d2 < 4; d2++)
#pragma unroll
    for (int r = 0; r < 4; r++) {
      const int iG = i0 + w * 16 + qd * 4 + r;
      ab[(size_t)(b * S_ + iG) * 1024 + h * 64 + d2 * 16 + lr] = f2bf(accO[d2][r] * inv[r]);
    }
}

// ---------------- launch ----------------
extern "C" void kernel_launch(void* const* d_in, const int* in_sizes, int n_in,
                              void* d_out, int out_size, void* d_ws, size_t ws_size,
                              hipStream_t stream) {
  const float* hidden = (const float*)d_in[0];
  const float* pos    = (const float*)d_in[1];
  const float* memory = (const float*)d_in[2];
  // d_in[3] = mask (bool) — causality applied analytically, unused
  const float* Wq = (const float*)d_in[4];
  const float* Wk = (const float*)d_in[5];
  const float* Wv = (const float*)d_in[6];
  const float* Wo = (const float*)d_in[7];
  const float* gamma = (const float*)d_in[8];
  const float* beta  = (const float*)d_in[9];

  char* ws = (char*)d_ws;
  u16* cln  = (u16*)(ws);               // 8 MB
  u16* qb   = (u16*)(ws + 8388608);     // 4 MB (pre-scaled 1/32)
  u16* kb   = (u16*)(ws + 12582912);    // 8 MB
  u16* vbT  = (u16*)(ws + 20971520);    // 8 MB
  u16* ab   = (u16*)(ws + 29360128);    // 4 MB
  u16* WqT  = (u16*)(ws + 33554432);    // 4 x 2 MB contiguous (WqT|WkT|WvT|WoT)
  u16* WkT  = WqT + 1048576;
  u16* WvT  = WkT + 1048576;
  u16* WoT  = WvT + 1048576;
  u16* posT = (u16*)(ws + 41943040);    // 0.56 MB tiled pos (144-group stride)

  prep_kernel<<<dim3(5256), 256, 0, stream>>>(
      hidden, memory, gamma, beta, cln,
      Wq, Wk, Wv, Wo, WqT, WkT, WvT, WoT, pos, posT);
  gemm_qkv_kernel<<<dim3(24, 32), 256, 0, stream>>>(cln, WqT, qb, kb, vbT);
  attn_kernel<<<dim3(S_ / 64, H_, B_), 256, 0, stream>>>(qb, kb, vbT, posT, ab);
  out_gemm_kernel<<<dim3(16, 16), 256, 0, stream>>>(ab, WoT, cln, (float*)d_out);
}